// Round 17
// baseline (1862.815 us; speedup 1.0000x reference)
//
#include <hip/hip_runtime.h>
#include <hip/hip_bf16.h>

#define N_NODES 50000
#define N_EDGES 800000
#define FIN 92
#define FD 128
#define DE 50
#define NL 3
#define NG 256
#define MPAD 130
#define NW 8
#define WEDGE (NW * 16)          // edges per wave
#define BEDGE (2 * WEDGE)        // edges per block (2 waves)

typedef short short8 __attribute__((ext_vector_type(8)));
typedef float f32x4 __attribute__((ext_vector_type(4)));

__device__ __forceinline__ unsigned short f2bf(float f) {
    unsigned u = __builtin_bit_cast(unsigned, f);
    unsigned r = (u + 0x7FFFu + ((u >> 16) & 1u)) >> 16;
    return (unsigned short)r;
}
__device__ __forceinline__ float bf2f(unsigned short b) {
    unsigned u = ((unsigned)b) << 16;
    return __builtin_bit_cast(float, u);
}
__device__ __forceinline__ unsigned pack2(float a, float b) {
    return (unsigned)f2bf(a) | ((unsigned)f2bf(b) << 16);
}

// mlds stored-pos p (hi*32 + nf*4 + r) -> true feature  (for agg write)
__device__ __forceinline__ int posFeat(int p) {
    return ((p >> 2) & 7) * 16 + ((p >> 5) << 2) + (p & 3);
}
// P stored-pos p (i*32 + hi*8 + j) -> true feature  (line-coalesced gather layout)
__device__ __forceinline__ int posFeat2(int p) {
    int q = ((p >> 5) << 3) | (p & 7);
    return ((q >> 2) << 4) + (((p >> 3) & 3) << 2) + (q & 3);
}

// ===== unified all-bf16 MFMA GEMM: A[M][K] bf16, Bt[NT*64][K] bf16 ([n][k]) =====
template<int K, int NT, int RELU, int BIAS, int OUTMODE>
__global__ __launch_bounds__(256) void gemm_bbg_kernel(
    const unsigned short* __restrict__ Abf, const unsigned short* __restrict__ Bt,
    const float* __restrict__ bias, void* __restrict__ Cout, void* __restrict__ Cout2, int M)
{
    __shared__ short Alds[64][K + 8];
    __shared__ short Blds[64][K + 8];
    const int tid = threadIdx.x;
    const int m0 = blockIdx.x * 64;
    constexpr int SEG = K / 8;
    constexpr int Nc = NT * 64;

    for (int i = tid; i < 64 * SEG; i += 256) {
        int r = i / SEG, sg = i - r * SEG;
        int row = m0 + r;
        short8 va = (row < M) ? *(const short8*)&Abf[(size_t)row * K + sg * 8] : (short8)0;
        *(short8*)&Alds[r][sg * 8] = va;
    }

    const int wv = tid >> 6, lane = tid & 63;
    const int lr = lane & 15, lk = (lane >> 4) * 8;

    for (int nt = 0; nt < NT; ++nt) {
        __syncthreads();   // prev tile consumed (also orders A-stage at nt=0)
        for (int i = tid; i < 64 * SEG; i += 256) {
            int r = i / SEG, sg = i - r * SEG;
            *(short8*)&Blds[r][sg * 8] = *(const short8*)&Bt[(size_t)(nt * 64 + r) * K + sg * 8];
        }
        __syncthreads();

        f32x4 acc[4];
#pragma unroll
        for (int i = 0; i < 4; ++i) acc[i] = (f32x4)0.f;
#pragma unroll
        for (int k0 = 0; k0 < K; k0 += 32) {
            short8 a = *(const short8*)&Alds[wv * 16 + lr][k0 + lk];
#pragma unroll
            for (int nf = 0; nf < 4; ++nf) {
                short8 b = *(const short8*)&Blds[nf * 16 + lr][k0 + lk];
                acc[nf] = __builtin_amdgcn_mfma_f32_16x16x32_bf16(a, b, acc[nf], 0, 0, 0);
            }
        }
#pragma unroll
        for (int nf = 0; nf < 4; ++nf) {
#pragma unroll
            for (int r = 0; r < 4; ++r) {
                int row = m0 + wv * 16 + (lane >> 4) * 4 + r;
                int col = nt * 64 + nf * 16 + lr;
                if (row < M) {
                    float v = acc[nf][r];
                    if (BIAS) v += bias[col];
                    if (RELU) v = fmaxf(v, 0.f);
                    if (OUTMODE == 1) {
                        ((unsigned short*)Cout)[(size_t)row * Nc + col] = f2bf(v);
                    } else {
                        ((float*)Cout)[(size_t)row * Nc + col] = v;
                        ((unsigned short*)Cout2)[(size_t)row * Nc + col] = f2bf(v);
                    }
                }
            }
        }
    }
}

// -------- x fp32 [N][92] -> bf16 padded [N][96] --------
__global__ __launch_bounds__(256) void x2bf_kernel(
    const float* __restrict__ x, unsigned short* __restrict__ xbf)
{
    int i = blockIdx.x * 256 + threadIdx.x;
    if (i >= N_NODES * 96) return;
    int row = i / 96, k = i - row * 96;
    float v = (k < FIN) ? __builtin_nontemporal_load(&x[(size_t)row * FIN + k]) : 0.f;
    xbf[i] = f2bf(v);
}

// -------- build transposed bf16 embed weights w0T[128][96], w1T[128][128] --------
__global__ __launch_bounds__(256) void build_wemb_kernel(
    const float* __restrict__ w_emb0, const float* __restrict__ w_emb1,
    unsigned short* __restrict__ w0T, unsigned short* __restrict__ w1T)
{
    int i = blockIdx.x * 256 + threadIdx.x;
    if (i < 128 * 96) {
        int n = i / 96, k = i - n * 96;
        w0T[i] = (k < FIN) ? f2bf(w_emb0[(size_t)k * FD + n]) : 0;
    }
    if (i < 128 * 128) {
        int n = i >> 7, k = i & 127;
        w1T[i] = f2bf(w_emb1[(size_t)k * FD + n]);
    }
}

// -------- build col-PERMUTED bf16 node-proj weights BcatT[l][512][128] + bias bcatF[l][512] --
__global__ __launch_bounds__(256) void build_bcatT_kernel(
    const float* __restrict__ wf, const float* __restrict__ wsw,
    const float* __restrict__ bfb, const float* __restrict__ bsb,
    unsigned short* __restrict__ BcatT, float* __restrict__ bcatF)
{
    int i = blockIdx.x * 256 + threadIdx.x;
    if (i < NL * 512 * 128) {
        int l = i / (512 * 128);
        int r = i - l * 512 * 128;
        int n = r >> 7, k = r & 127;
        int seg = n >> 7, p = n & 127;
        int nf_ = seg * 128 + posFeat2(p);
        const float* Wm = (nf_ < 256) ? wf : wsw;
        int jj = nf_ & 255;
        int krow = (jj < 128) ? k : (128 + k);
        int col = jj & 127;
        BcatT[i] = f2bf(Wm[((size_t)l * 306 + krow) * FD + col]);
    }
    if (i < NL * 512) {
        int l = i >> 9, n = i & 511;
        int seg = n >> 7, p = n & 127;
        float v = 0.f;
        if (seg == 0) v = bfb[l * FD + posFeat2(p)];
        else if (seg == 2) v = bsb[l * FD + posFeat2(p)];
        bcatF[i] = v;
    }
}

// -------- build transposed bf16 edge-proj weights WecatT[l][256][64] --------
__global__ __launch_bounds__(256) void build_wecat_kernel(
    const float* __restrict__ wf, const float* __restrict__ wsw,
    unsigned short* __restrict__ WecatT)
{
    int i = blockIdx.x * 256 + threadIdx.x;
    if (i >= NL * 256 * 64) return;
    int l = i / (256 * 64);
    int r = i - l * 256 * 64;
    int col = r >> 6, k = r & 63;
    float v = 0.f;
    if (k < DE) {
        const float* W = (col < 128) ? wf : wsw;
        v = W[((size_t)l * 306 + 256 + k) * FD + (col & 127)];
    }
    WecatT[i] = f2bf(v);
}

// ================= dst-sorted edge permutation (counting sort) =================
__global__ __launch_bounds__(256) void hist_kernel(
    const int* __restrict__ dstIdx, int* __restrict__ counts)
{
    int e = blockIdx.x * 256 + threadIdx.x;
    if (e < N_EDGES) atomicAdd(&counts[dstIdx[e]], 1);
}

__global__ __launch_bounds__(1024) void scan_kernel(
    const int* __restrict__ counts, int* __restrict__ cursor)
{
    __shared__ int part[1024];
    const int t = threadIdx.x;
    const int CH = 49;  // 1024*49 >= 50000
    const int base = t * CH;
    int s = 0;
    for (int i = 0; i < CH; ++i) {
        int idx = base + i;
        if (idx < N_NODES) s += counts[idx];
    }
    part[t] = s;
    __syncthreads();
    int v = s;
    for (int off = 1; off < 1024; off <<= 1) {
        int add = (t >= off) ? part[t - off] : 0;
        __syncthreads();
        v += add;
        part[t] = v;
        __syncthreads();
    }
    int pre = (t == 0) ? 0 : part[t - 1];
    for (int i = 0; i < CH; ++i) {
        int idx = base + i;
        if (idx < N_NODES) {
            cursor[idx] = pre;
            pre += counts[idx];
        }
    }
}

__global__ __launch_bounds__(256) void scatter_kernel(
    const int* __restrict__ eidx, int* __restrict__ cursor,
    int* __restrict__ perm, int* __restrict__ srcS, int* __restrict__ dstS)
{
    int e = blockIdx.x * 256 + threadIdx.x;
    if (e >= N_EDGES) return;
    int d = eidx[N_EDGES + e];
    int pos = atomicAdd(&cursor[d], 1);
    perm[pos] = e;
    srcS[pos] = eidx[e];
    dstS[pos] = d;
}

// -------- edge_attr -> bf16 padded [E][64], dst-sorted; u64 loads + packed u32 stores -----
__global__ __launch_bounds__(256) void ea2bf2_kernel(
    const float* __restrict__ ea, const int* __restrict__ perm,
    unsigned* __restrict__ out)
{
    int t = blockIdx.x * 256 + threadIdx.x;   // (edge, j) with j < 32 u32-slots
    if (t >= N_EDGES * 32) return;
    int e = t >> 5, j = t & 31;
    unsigned v = 0;
    if (j < 25) {
        int pe = perm[e];
        unsigned long long u = __builtin_nontemporal_load(
            (const unsigned long long*)(ea + (size_t)pe * DE) + j);
        float lo = __builtin_bit_cast(float, (unsigned)u);
        float hi = __builtin_bit_cast(float, (unsigned)(u >> 32));
        v = pack2(lo, hi);
    }
    out[(size_t)e * 32 + j] = v;
}

// ===== msg16: wave-independent zero-barrier (msg15) + NW=8 + setprio on MFMA =====
// Wave w owns edges [base + w*WEDGE, base + (w+1)*WEDGE) as NW windows of 16.
__global__ __launch_bounds__(128, 4) void msg16_kernel(
    const unsigned short* __restrict__ Pbf,     // [N][512] bf16, posFeat2-permuted per 128-seg
    const unsigned short* __restrict__ eabf,    // [E][64] bf16, dst-sorted
    const unsigned short* __restrict__ WecatT,  // [256][64] bf16 (layer offset applied)
    const int* __restrict__ srcS, const int* __restrict__ dstS,
    float* __restrict__ agg)
{
    __shared__ float mlds[2][16][MPAD];
    __shared__ int dlds[BEDGE + 2];
    const int tid = threadIdx.x;
    const int base = blockIdx.x * BEDGE;

    for (int i = tid; i < BEDGE + 2; i += 128) {
        int ge = base - 1 + i;
        int v;
        if (ge < 0) v = -1;
        else if (ge >= N_EDGES) v = -2;
        else v = __builtin_nontemporal_load(&dstS[ge]);
        dlds[i] = v;
    }

    const int w = tid >> 6, lane = tid & 63;
    const int lr = lane & 15, hi = lane >> 4;
    const int wspan = w * WEDGE;              // wave's first edge (block-local)

    // prefetch window 0's src index + ea fragments
    int s_cur = __builtin_nontemporal_load(&srcS[base + wspan + lr]);
    short8 b0_cur = __builtin_nontemporal_load((const short8*)&eabf[(size_t)(base + wspan + lr) * 64 + hi * 8]);
    short8 b1_cur = __builtin_nontemporal_load((const short8*)&eabf[(size_t)(base + wspan + lr) * 64 + 32 + hi * 8]);

    __syncthreads();   // dlds ready (only barrier in the kernel)

    // phase-2 persistent state: lane owns cols (lane, lane+64) of its wave's edges
    float run0 = 0.f, run1 = 0.f;
    bool startsInside = (dlds[wspan + 1] != dlds[wspan]);
    const int fc0 = posFeat(lane);
    const int fc1 = posFeat(lane + 64);

#pragma unroll 1
    for (int wi = 0; wi < NW; ++wi) {
        const int jbase = wspan + wi * 16;    // block-local edge index of window start
        const int d = dlds[1 + jbase + lr];
        const int s = s_cur;
        const short8 b0 = b0_cur, b1 = b1_cur;

        if (wi + 1 < NW) {   // prefetch next window's indices/ea
            const int en = base + jbase + 16 + lr;
            s_cur = __builtin_nontemporal_load(&srcS[en]);
            b0_cur = __builtin_nontemporal_load((const short8*)&eabf[(size_t)en * 64 + hi * 8]);
            b1_cur = __builtin_nontemporal_load((const short8*)&eabf[(size_t)en * 64 + 32 + hi * 8]);
        }

        const unsigned short* pdrow = Pbf + (size_t)d * 512 + hi * 8;
        const unsigned short* psrow = Pbf + (size_t)s * 512 + hi * 8;

        // ---- pass S: soft pre-acts (stored seg 2/3) ----
        unsigned pvp[16];
        {
            short8 pds[4], pss[4];
#pragma unroll
            for (int i = 0; i < 4; ++i) {
                pds[i] = *(const short8*)(pdrow + 256 + i * 32);
                pss[i] = *(const short8*)(psrow + 384 + i * 32);
            }
            f32x4 accS[8];
#pragma unroll
            for (int i = 0; i < 8; ++i) accS[i] = (f32x4)0.f;
            __builtin_amdgcn_s_setprio(1);
#pragma unroll
            for (int nf = 0; nf < 8; ++nf) {
                short8 a0 = *(const short8*)&WecatT[(size_t)((nf + 8) * 16 + lr) * 64 + hi * 8];
                short8 a1 = *(const short8*)&WecatT[(size_t)((nf + 8) * 16 + lr) * 64 + 32 + hi * 8];
                accS[nf] = __builtin_amdgcn_mfma_f32_16x16x32_bf16(a0, b0, accS[nf], 0, 0, 0);
                accS[nf] = __builtin_amdgcn_mfma_f32_16x16x32_bf16(a1, b1, accS[nf], 0, 0, 0);
            }
            __builtin_amdgcn_s_setprio(0);
#pragma unroll
            for (int j = 0; j < 16; ++j) {
                const int k0 = 2 * j, k1 = 2 * j + 1;
                float v0 = accS[k0 >> 2][k0 & 3] + bf2f((unsigned short)pds[k0 >> 3][k0 & 7])
                                                 + bf2f((unsigned short)pss[k0 >> 3][k0 & 7]);
                float v1 = accS[k1 >> 2][k1 & 3] + bf2f((unsigned short)pds[k1 >> 3][k1 & 7])
                                                 + bf2f((unsigned short)pss[k1 >> 3][k1 & 7]);
                pvp[j] = pack2(v0, v1);
            }
        }

        // ---- pass F: filter pre-acts (stored seg 0/1) + gate -> mlds[w] ----
        {
            short8 pdf[4], psf[4];
#pragma unroll
            for (int i = 0; i < 4; ++i) {
                pdf[i] = *(const short8*)(pdrow + i * 32);
                psf[i] = *(const short8*)(psrow + 128 + i * 32);
            }
            f32x4 accF[8];
#pragma unroll
            for (int i = 0; i < 8; ++i) accF[i] = (f32x4)0.f;
            __builtin_amdgcn_s_setprio(1);
#pragma unroll
            for (int nf = 0; nf < 8; ++nf) {
                short8 a0 = *(const short8*)&WecatT[(size_t)(nf * 16 + lr) * 64 + hi * 8];
                short8 a1 = *(const short8*)&WecatT[(size_t)(nf * 16 + lr) * 64 + 32 + hi * 8];
                accF[nf] = __builtin_amdgcn_mfma_f32_16x16x32_bf16(a0, b0, accF[nf], 0, 0, 0);
                accF[nf] = __builtin_amdgcn_mfma_f32_16x16x32_bf16(a1, b1, accF[nf], 0, 0, 0);
            }
            __builtin_amdgcn_s_setprio(0);
#pragma unroll
            for (int nf = 0; nf < 8; ++nf) {
                f32x4 m;
#pragma unroll
                for (int r = 0; r < 4; ++r) {
                    const int q = nf * 4 + r;
                    float pf = accF[nf][r] + bf2f((unsigned short)pdf[q >> 3][q & 7])
                                           + bf2f((unsigned short)psf[q >> 3][q & 7]);
                    unsigned pw = pvp[q >> 1];
                    float pv = (q & 1) ? __builtin_bit_cast(float, pw & 0xFFFF0000u)
                                       : bf2f((unsigned short)(pw & 0xFFFFu));
                    float sig = 1.f / (1.f + __expf(-pf));
                    float tt = __expf(-fabsf(pv));
                    float sp = fmaxf(pv, 0.f) + __logf(1.f + tt);
                    m[r] = sig * sp;
                }
                *(f32x4*)&mlds[w][lr][hi * 32 + nf * 4] = m;
            }
        }
        // no barrier: pass-F writes and phase-2 reads stay within this wave (lgkmcnt order)

        // ---- phase 2: lane walks its wave's 16 edges for cols (lane, lane+64) ----
        {
#pragma unroll 4
            for (int ee = 0; ee < 16; ++ee) {
                const int j = jbase + ee;
                run0 += mlds[w][ee][lane];
                run1 += mlds[w][ee][lane + 64];
                int de = dlds[j + 1];
                int dnext = dlds[j + 2];
                if (de != dnext) {   // run ends here (uniform across the wave)
                    if (startsInside) {
                        agg[(size_t)de * FD + fc0] = run0;
                        agg[(size_t)de * FD + fc1] = run1;
                    } else {
                        unsafeAtomicAdd(&agg[(size_t)de * FD + fc0], run0);
                        unsafeAtomicAdd(&agg[(size_t)de * FD + fc1], run1);
                    }
                    run0 = 0.f; run1 = 0.f;
                    startsInside = true;
                }
            }
        }
    }
    if (run0 != 0.f || run1 != 0.f) {   // tail run continues past this wave's span
        unsafeAtomicAdd(&agg[(size_t)dlds[wspan + WEDGE] * FD + fc0], run0);
        unsafeAtomicAdd(&agg[(size_t)dlds[wspan + WEDGE] * FD + fc1], run1);
    }
}

// -------- BatchNorm stats over N rows (LDS pair-reduce, then one atomic per col) --------
__global__ __launch_bounds__(256) void bn_stats_kernel(
    const float* __restrict__ agg, float* __restrict__ stats)
{
    __shared__ float sl[256], sql[256];
    const int tid = threadIdx.x;
    const int f = tid & 127;
    float s = 0.f, sq = 0.f;
    for (int row = blockIdx.x * 2 + (tid >> 7); row < N_NODES; row += gridDim.x * 2) {
        float v = agg[(size_t)row * FD + f];
        s += v; sq += v * v;
    }
    sl[tid] = s; sql[tid] = sq;
    __syncthreads();
    if (tid < 128) {
        unsafeAtomicAdd(&stats[f], sl[tid] + sl[tid + 128]);
        unsafeAtomicAdd(&stats[128 + f], sql[tid] + sql[tid + 128]);
    }
}

// -------- h = relu(h + BN(agg)); write fp32 + bf16; atomicMax per-graph --------
__global__ __launch_bounds__(256) void bn_update_kernel(
    float* __restrict__ h, unsigned short* __restrict__ hbf,
    const float* __restrict__ agg,
    const float* __restrict__ stats, const float* __restrict__ g,
    const float* __restrict__ b, const int* __restrict__ batch,
    float* __restrict__ gmax)
{
    const int tid = threadIdx.x;
    const int row = blockIdx.x * 2 + (tid >> 7);
    if (row >= N_NODES) return;
    const int f = tid & 127;
    const float inv = 1.f / (float)N_NODES;
    float mu = stats[f] * inv;
    float var = stats[128 + f] * inv - mu * mu;
    float rs = rsqrtf(var + 1e-5f);
    size_t idx = (size_t)row * FD + f;
    float v = h[idx] + (agg[idx] - mu) * rs * g[f] + b[f];
    v = fmaxf(v, 0.f);
    h[idx] = v;
    hbf[idx] = f2bf(v);
    atomicMax((unsigned*)&gmax[batch[row] * FD + f], __float_as_uint(v));
}

// -------- final layer: gmax only (h/hbf dead afterwards) --------
__global__ __launch_bounds__(256) void bn_gmax_kernel(
    const float* __restrict__ h, const float* __restrict__ agg,
    const float* __restrict__ stats, const float* __restrict__ g,
    const float* __restrict__ b, const int* __restrict__ batch,
    float* __restrict__ gmax)
{
    const int tid = threadIdx.x;
    const int row = blockIdx.x * 2 + (tid >> 7);
    if (row >= N_NODES) return;
    const int f = tid & 127;
    const float inv = 1.f / (float)N_NODES;
    float mu = stats[f] * inv;
    float var = stats[128 + f] * inv - mu * mu;
    float rs = rsqrtf(var + 1e-5f);
    size_t idx = (size_t)row * FD + f;
    float v = h[idx] + (agg[idx] - mu) * rs * g[f] + b[f];
    v = fmaxf(v, 0.f);
    atomicMax((unsigned*)&gmax[batch[row] * FD + f], __float_as_uint(v));
}

__global__ __launch_bounds__(256) void gf_acc_kernel(float* __restrict__ gf, const float* __restrict__ gmax)
{
    int i = blockIdx.x * 256 + threadIdx.x;
    gf[i] += gmax[i];
}

// -------- head --------
__global__ __launch_bounds__(128) void head_y_kernel(
    const float* __restrict__ gf, const float* __restrict__ w1,
    const float* __restrict__ b1, float* __restrict__ y)
{
    __shared__ float row[128];
    int g = blockIdx.x, j = threadIdx.x;
    row[j] = gf[g * FD + j];
    __syncthreads();
    float acc = b1[j];
    for (int k = 0; k < FD; ++k) acc = fmaf(row[k], w1[k * FD + j], acc);
    y[g * FD + j] = acc;
}

__global__ __launch_bounds__(128) void head_stats_kernel(
    const float* __restrict__ y, float* __restrict__ hstat)
{
    int f = threadIdx.x;
    float s = 0.f, sq = 0.f;
    for (int g = 0; g < NG; ++g) { float v = y[g * FD + f]; s += v; sq += v * v; }
    float mu = s / (float)NG;
    float var = sq / (float)NG - mu * mu;
    hstat[f] = mu;
    hstat[128 + f] = rsqrtf(var + 1e-5f);
}

__global__ __launch_bounds__(128) void head_out_kernel(
    const float* __restrict__ y, const float* __restrict__ hstat,
    const float* __restrict__ bng, const float* __restrict__ bnb,
    const float* __restrict__ w2, const float* __restrict__ b2,
    float* __restrict__ out)
{
    __shared__ float part[2];
    int g = blockIdx.x, f = threadIdx.x;
    float v = (y[g * FD + f] - hstat[f]) * hstat[128 + f] * bng[f] + bnb[f];
    v = fmaxf(v, 0.f) * w2[f];
    for (int o = 32; o > 0; o >>= 1) v += __shfl_down(v, o);
    if ((f & 63) == 0) part[f >> 6] = v;
    __syncthreads();
    if (f == 0) out[g] = part[0] + part[1] + b2[0];
}

extern "C" void kernel_launch(void* const* d_in, const int* in_sizes, int n_in,
                              void* d_out, int out_size, void* d_ws, size_t ws_size,
                              hipStream_t stream)
{
    const float* x        = (const float*)d_in[0];
    const float* edge_attr= (const float*)d_in[1];
    const float* w_emb0   = (const float*)d_in[2];
    const float* w_emb1   = (const float*)d_in[3];
    const float* wf       = (const float*)d_in[4];
    const float* bf       = (const float*)d_in[5];
    const float* wsw      = (const float*)d_in[6];
    const float* bs       = (const float*)d_in[7];
    const float* bn_g     = (const float*)d_in[8];
    const float* bn_b     = (const float*)d_in[9];
    const float* w1       = (const float*)d_in[10];
    const float* b1       = (const float*)d_in[11];
    const float* bng      = (const float*)d_in[12];
    const float* bnb      = (const float*)d_in[13];
    const float* w2       = (const float*)d_in[14];
    const float* b2       = (const float*)d_in[15];
    const int*   eidx     = (const int*)d_in[16];   // [2][E]: row0=src, row1=dst
    const int*   batch    = (const int*)d_in[17];

    char* base = (char*)d_ws;
    size_t off = 0;
    auto alloc = [&](size_t bytes) -> void* {
        void* p = base + off;
        off += (bytes + 255) & ~(size_t)255;
        return p;
    };
    float*          h      = (float*)alloc((size_t)N_NODES * FD * 4);
    unsigned short* hbf    = (unsigned short*)alloc((size_t)N_NODES * FD * 2);
    unsigned short* Pbf    = (unsigned short*)alloc((size_t)N_NODES * 512 * 2);
    // agg|stats|gmax contiguous -> single per-layer memset
    float*          agg    = (float*)alloc((size_t)N_NODES * FD * 4);   // also embed tmp + sort scratch
    float*          stats  = (float*)alloc(256 * 4);
    float*          gmax   = (float*)alloc((size_t)NG * FD * 4);
    unsigned short* BcatT  = (unsigned short*)alloc((size_t)NL * 512 * 128 * 2);
    unsigned short* WecatT = (unsigned short*)alloc((size_t)NL * 256 * 64 * 2);
    float*          bcatF  = (float*)alloc((size_t)NL * 512 * 4);
    unsigned short* eabf   = (unsigned short*)alloc((size_t)N_EDGES * 64 * 2);
    int*            srcS   = (int*)alloc((size_t)N_EDGES * 4);
    int*            dstS   = (int*)alloc((size_t)N_EDGES * 4);
    unsigned short* xbf    = (unsigned short*)alloc((size_t)N_NODES * 96 * 2);
    unsigned short* w0T    = (unsigned short*)alloc((size_t)128 * 96 * 2);
    unsigned short* w1T    = (unsigned short*)alloc((size_t)128 * 128 * 2);
    float*          gf     = (float*)alloc((size_t)NG * FD * 4);
    float*          y      = (float*)alloc((size_t)NG * FD * 4);
    float*          hstat  = (float*)alloc(256 * 4);

    const size_t msetBytes = (size_t)((char*)gmax + (size_t)NG * FD * 4 - (char*)agg);

    // sort scratch overlaid on agg (dead until layer loop; all sort users complete first)
    int* perm   = (int*)agg;               // [E]
    int* counts = perm + N_EDGES;          // [N]
    int* cursor = counts + N_NODES;        // [N]
    // t0 (embed intermediate, bf16 [N][128]) also overlays agg (after ea2bf consumed perm)
    unsigned short* t0bf = (unsigned short*)agg;

    const int MB = (N_NODES + 63) / 64;  // 782

    // ---- dst-sort the edges (once, reused across layers) ----
    hipMemsetAsync(counts, 0, (size_t)N_NODES * 4, stream);
    hist_kernel<<<(N_EDGES + 255) / 256, 256, 0, stream>>>(eidx + N_EDGES, counts);
    scan_kernel<<<1, 1024, 0, stream>>>(counts, cursor);
    scatter_kernel<<<(N_EDGES + 255) / 256, 256, 0, stream>>>(eidx, cursor, perm, srcS, dstS);
    ea2bf2_kernel<<<(N_EDGES * 32) / 256, 256, 0, stream>>>(edge_attr, perm, (unsigned*)eabf);

    build_bcatT_kernel<<<(NL * 512 * 128 + 255) / 256, 256, 0, stream>>>(wf, wsw, bf, bs, BcatT, bcatF);
    build_wecat_kernel<<<(NL * 256 * 64 + 255) / 256, 256, 0, stream>>>(wf, wsw, WecatT);
    build_wemb_kernel<<<64, 256, 0, stream>>>(w_emb0, w_emb1, w0T, w1T);
    x2bf_kernel<<<(N_NODES * 96 + 255) / 256, 256, 0, stream>>>(x, xbf);

    // embedding MLP (all-bf16 GEMMs): t0 = relu(xbf@w0); h(+hbf) = t0@w1
    gemm_bbg_kernel<96, 2, 1, 0, 1><<<MB, 256, 0, stream>>>(xbf, w0T, nullptr, t0bf, nullptr, N_NODES);
    gemm_bbg_kernel<128, 2, 0, 0, 2><<<MB, 256, 0, stream>>>(t0bf, w1T, nullptr, h, hbf, N_NODES);

    hipMemsetAsync(gf, 0, (size_t)NG * FD * 4, stream);

    for (int l = 0; l < NL; ++l) {
        hipMemsetAsync(agg, 0, msetBytes, stream);   // zeros agg + stats + gmax

        // P = hbf @ BcatT[l]^T + bcatF[l]  -> bf16 [N][512], posFeat2-permuted
        gemm_bbg_kernel<128, 8, 0, 1, 1><<<MB, 256, 0, stream>>>(
            hbf, BcatT + (size_t)l * 512 * 128, bcatF + (size_t)l * 512, Pbf, nullptr, N_NODES);

        msg16_kernel<<<N_EDGES / BEDGE, 128, 0, stream>>>(
            Pbf, eabf, WecatT + (size_t)l * 256 * 64, srcS, dstS, agg);

        bn_stats_kernel<<<256, 256, 0, stream>>>(agg, stats);
        if (l < NL - 1) {
            bn_update_kernel<<<(N_NODES + 1) / 2, 256, 0, stream>>>(
                h, hbf, agg, stats, bn_g + l * FD, bn_b + l * FD, batch, gmax);
        } else {
            bn_gmax_kernel<<<(N_NODES + 1) / 2, 256, 0, stream>>>(
                h, agg, stats, bn_g + l * FD, bn_b + l * FD, batch, gmax);
        }
        gf_acc_kernel<<<(NG * FD) / 256, 256, 0, stream>>>(gf, gmax);
    }

    head_y_kernel<<<NG, 128, 0, stream>>>(gf, w1, b1, y);
    head_stats_kernel<<<1, 128, 0, stream>>>(y, hstat);
    head_out_kernel<<<NG, 128, 0, stream>>>(y, hstat, bng, bnb, w2, b2, (float*)d_out);
}

// Round 18
// 1276.688 us; speedup vs baseline: 1.4591x; 1.4591x over previous
//
#include <hip/hip_runtime.h>
#include <hip/hip_bf16.h>

#define N_NODES 50000
#define N_EDGES 800000
#define FIN 92
#define FD 128
#define DE 50
#define NL 3
#define NG 256
#define MPAD 130
#define NW 4

typedef short short8 __attribute__((ext_vector_type(8)));
typedef float f32x4 __attribute__((ext_vector_type(4)));

__device__ __forceinline__ unsigned short f2bf(float f) {
    unsigned u = __builtin_bit_cast(unsigned, f);
    unsigned r = (u + 0x7FFFu + ((u >> 16) & 1u)) >> 16;
    return (unsigned short)r;
}
__device__ __forceinline__ float bf2f(unsigned short b) {
    unsigned u = ((unsigned)b) << 16;
    return __builtin_bit_cast(float, u);
}
__device__ __forceinline__ unsigned pack2(float a, float b) {
    return (unsigned)f2bf(a) | ((unsigned)f2bf(b) << 16);
}

// mlds stored-pos p (hi*32 + nf*4 + r) -> true feature  (for agg write)
__device__ __forceinline__ int posFeat(int p) {
    return ((p >> 2) & 7) * 16 + ((p >> 5) << 2) + (p & 3);
}
// P stored-pos p (i*32 + hi*8 + j) -> true feature  (line-coalesced gather layout)
__device__ __forceinline__ int posFeat2(int p) {
    int q = ((p >> 5) << 3) | (p & 7);
    return ((q >> 2) << 4) + (((p >> 3) & 3) << 2) + (q & 3);
}

// ===== unified all-bf16 MFMA GEMM: A[M][K] bf16, Bt[NT*64][K] bf16 ([n][k]) =====
template<int K, int NT, int RELU, int BIAS, int OUTMODE>
__global__ __launch_bounds__(256) void gemm_bbg_kernel(
    const unsigned short* __restrict__ Abf, const unsigned short* __restrict__ Bt,
    const float* __restrict__ bias, void* __restrict__ Cout, void* __restrict__ Cout2, int M)
{
    __shared__ short Alds[64][K + 8];
    __shared__ short Blds[64][K + 8];
    const int tid = threadIdx.x;
    const int m0 = blockIdx.x * 64;
    constexpr int SEG = K / 8;
    constexpr int Nc = NT * 64;

    for (int i = tid; i < 64 * SEG; i += 256) {
        int r = i / SEG, sg = i - r * SEG;
        int row = m0 + r;
        short8 va = (row < M) ? *(const short8*)&Abf[(size_t)row * K + sg * 8] : (short8)0;
        *(short8*)&Alds[r][sg * 8] = va;
    }

    const int wv = tid >> 6, lane = tid & 63;
    const int lr = lane & 15, lk = (lane >> 4) * 8;

    for (int nt = 0; nt < NT; ++nt) {
        __syncthreads();   // prev tile consumed (also orders A-stage at nt=0)
        for (int i = tid; i < 64 * SEG; i += 256) {
            int r = i / SEG, sg = i - r * SEG;
            *(short8*)&Blds[r][sg * 8] = *(const short8*)&Bt[(size_t)(nt * 64 + r) * K + sg * 8];
        }
        __syncthreads();

        f32x4 acc[4];
#pragma unroll
        for (int i = 0; i < 4; ++i) acc[i] = (f32x4)0.f;
#pragma unroll
        for (int k0 = 0; k0 < K; k0 += 32) {
            short8 a = *(const short8*)&Alds[wv * 16 + lr][k0 + lk];
#pragma unroll
            for (int nf = 0; nf < 4; ++nf) {
                short8 b = *(const short8*)&Blds[nf * 16 + lr][k0 + lk];
                acc[nf] = __builtin_amdgcn_mfma_f32_16x16x32_bf16(a, b, acc[nf], 0, 0, 0);
            }
        }
#pragma unroll
        for (int nf = 0; nf < 4; ++nf) {
#pragma unroll
            for (int r = 0; r < 4; ++r) {
                int row = m0 + wv * 16 + (lane >> 4) * 4 + r;
                int col = nt * 64 + nf * 16 + lr;
                if (row < M) {
                    float v = acc[nf][r];
                    if (BIAS) v += bias[col];
                    if (RELU) v = fmaxf(v, 0.f);
                    if (OUTMODE == 1) {
                        ((unsigned short*)Cout)[(size_t)row * Nc + col] = f2bf(v);
                    } else {
                        ((float*)Cout)[(size_t)row * Nc + col] = v;
                        ((unsigned short*)Cout2)[(size_t)row * Nc + col] = f2bf(v);
                    }
                }
            }
        }
    }
}

// -------- x fp32 [N][92] -> bf16 padded [N][96] --------
__global__ __launch_bounds__(256) void x2bf_kernel(
    const float* __restrict__ x, unsigned short* __restrict__ xbf)
{
    int i = blockIdx.x * 256 + threadIdx.x;
    if (i >= N_NODES * 96) return;
    int row = i / 96, k = i - row * 96;
    float v = (k < FIN) ? __builtin_nontemporal_load(&x[(size_t)row * FIN + k]) : 0.f;
    xbf[i] = f2bf(v);
}

// -------- build transposed bf16 embed weights w0T[128][96], w1T[128][128] --------
__global__ __launch_bounds__(256) void build_wemb_kernel(
    const float* __restrict__ w_emb0, const float* __restrict__ w_emb1,
    unsigned short* __restrict__ w0T, unsigned short* __restrict__ w1T)
{
    int i = blockIdx.x * 256 + threadIdx.x;
    if (i < 128 * 96) {
        int n = i / 96, k = i - n * 96;
        w0T[i] = (k < FIN) ? f2bf(w_emb0[(size_t)k * FD + n]) : 0;
    }
    if (i < 128 * 128) {
        int n = i >> 7, k = i & 127;
        w1T[i] = f2bf(w_emb1[(size_t)k * FD + n]);
    }
}

// -------- build col-PERMUTED bf16 node-proj weights BcatT[l][512][128] + bias bcatF[l][512] --
__global__ __launch_bounds__(256) void build_bcatT_kernel(
    const float* __restrict__ wf, const float* __restrict__ wsw,
    const float* __restrict__ bfb, const float* __restrict__ bsb,
    unsigned short* __restrict__ BcatT, float* __restrict__ bcatF)
{
    int i = blockIdx.x * 256 + threadIdx.x;
    if (i < NL * 512 * 128) {
        int l = i / (512 * 128);
        int r = i - l * 512 * 128;
        int n = r >> 7, k = r & 127;
        int seg = n >> 7, p = n & 127;
        int nf_ = seg * 128 + posFeat2(p);
        const float* Wm = (nf_ < 256) ? wf : wsw;
        int jj = nf_ & 255;
        int krow = (jj < 128) ? k : (128 + k);
        int col = jj & 127;
        BcatT[i] = f2bf(Wm[((size_t)l * 306 + krow) * FD + col]);
    }
    if (i < NL * 512) {
        int l = i >> 9, n = i & 511;
        int seg = n >> 7, p = n & 127;
        float v = 0.f;
        if (seg == 0) v = bfb[l * FD + posFeat2(p)];
        else if (seg == 2) v = bsb[l * FD + posFeat2(p)];
        bcatF[i] = v;
    }
}

// -------- build transposed bf16 edge-proj weights WecatT[l][256][64] --------
__global__ __launch_bounds__(256) void build_wecat_kernel(
    const float* __restrict__ wf, const float* __restrict__ wsw,
    unsigned short* __restrict__ WecatT)
{
    int i = blockIdx.x * 256 + threadIdx.x;
    if (i >= NL * 256 * 64) return;
    int l = i / (256 * 64);
    int r = i - l * 256 * 64;
    int col = r >> 6, k = r & 63;
    float v = 0.f;
    if (k < DE) {
        const float* W = (col < 128) ? wf : wsw;
        v = W[((size_t)l * 306 + 256 + k) * FD + (col & 127)];
    }
    WecatT[i] = f2bf(v);
}

// ================= dst-sorted edge permutation (counting sort) =================
__global__ __launch_bounds__(256) void hist_kernel(
    const int* __restrict__ dstIdx, int* __restrict__ counts)
{
    int e = blockIdx.x * 256 + threadIdx.x;
    if (e < N_EDGES) atomicAdd(&counts[dstIdx[e]], 1);
}

__global__ __launch_bounds__(1024) void scan_kernel(
    const int* __restrict__ counts, int* __restrict__ cursor)
{
    __shared__ int part[1024];
    const int t = threadIdx.x;
    const int CH = 49;  // 1024*49 >= 50000
    const int base = t * CH;
    int s = 0;
    for (int i = 0; i < CH; ++i) {
        int idx = base + i;
        if (idx < N_NODES) s += counts[idx];
    }
    part[t] = s;
    __syncthreads();
    int v = s;
    for (int off = 1; off < 1024; off <<= 1) {
        int add = (t >= off) ? part[t - off] : 0;
        __syncthreads();
        v += add;
        part[t] = v;
        __syncthreads();
    }
    int pre = (t == 0) ? 0 : part[t - 1];
    for (int i = 0; i < CH; ++i) {
        int idx = base + i;
        if (idx < N_NODES) {
            cursor[idx] = pre;
            pre += counts[idx];
        }
    }
}

__global__ __launch_bounds__(256) void scatter_kernel(
    const int* __restrict__ eidx, int* __restrict__ cursor,
    int* __restrict__ perm, int* __restrict__ srcS, int* __restrict__ dstS)
{
    int e = blockIdx.x * 256 + threadIdx.x;
    if (e >= N_EDGES) return;
    int d = eidx[N_EDGES + e];
    int pos = atomicAdd(&cursor[d], 1);
    perm[pos] = e;
    srcS[pos] = eidx[e];
    dstS[pos] = d;
}

// -------- edge_attr -> bf16 padded [E][64], dst-sorted; u64 loads + packed u32 stores -----
__global__ __launch_bounds__(256) void ea2bf2_kernel(
    const float* __restrict__ ea, const int* __restrict__ perm,
    unsigned* __restrict__ out)
{
    int t = blockIdx.x * 256 + threadIdx.x;   // (edge, j) with j < 32 u32-slots
    if (t >= N_EDGES * 32) return;
    int e = t >> 5, j = t & 31;
    unsigned v = 0;
    if (j < 25) {
        int pe = perm[e];
        unsigned long long u = __builtin_nontemporal_load(
            (const unsigned long long*)(ea + (size_t)pe * DE) + j);
        float lo = __builtin_bit_cast(float, (unsigned)u);
        float hi = __builtin_bit_cast(float, (unsigned)(u >> 32));
        v = pack2(lo, hi);
    }
    out[(size_t)e * 32 + j] = v;
}

// ===== msg15: wave-independent, ZERO barriers in main loop (proven R15 form) =====
__global__ __launch_bounds__(128) void msg15_kernel(
    const unsigned short* __restrict__ Pbf,     // [N][512] bf16, posFeat2-permuted per 128-seg
    const unsigned short* __restrict__ eabf,    // [E][64] bf16, dst-sorted
    const unsigned short* __restrict__ WecatT,  // [256][64] bf16 (layer offset applied)
    const int* __restrict__ srcS, const int* __restrict__ dstS,
    float* __restrict__ agg)
{
    __shared__ float mlds[2][16][MPAD];
    __shared__ int dlds[NW * 32 + 2];
    const int tid = threadIdx.x;
    const int base = blockIdx.x * (NW * 32);

    for (int i = tid; i < NW * 32 + 2; i += 128) {
        int ge = base - 1 + i;
        int v;
        if (ge < 0) v = -1;
        else if (ge >= N_EDGES) v = -2;
        else v = __builtin_nontemporal_load(&dstS[ge]);
        dlds[i] = v;
    }

    const int w = tid >> 6, lane = tid & 63;
    const int lr = lane & 15, hi = lane >> 4;
    const int wspan = w * 64;                 // wave's first edge (block-local)

    int s_cur = __builtin_nontemporal_load(&srcS[base + wspan + lr]);
    short8 b0_cur = __builtin_nontemporal_load((const short8*)&eabf[(size_t)(base + wspan + lr) * 64 + hi * 8]);
    short8 b1_cur = __builtin_nontemporal_load((const short8*)&eabf[(size_t)(base + wspan + lr) * 64 + 32 + hi * 8]);

    __syncthreads();   // dlds ready (only barrier in the kernel)

    float run0 = 0.f, run1 = 0.f;
    bool startsInside = (dlds[wspan + 1] != dlds[wspan]);
    const int fc0 = posFeat(lane);
    const int fc1 = posFeat(lane + 64);

#pragma unroll 1
    for (int wi = 0; wi < NW; ++wi) {
        const int jbase = wspan + wi * 16;
        const int d = dlds[1 + jbase + lr];
        const int s = s_cur;
        const short8 b0 = b0_cur, b1 = b1_cur;

        if (wi + 1 < NW) {
            const int en = base + jbase + 16 + lr;
            s_cur = __builtin_nontemporal_load(&srcS[en]);
            b0_cur = __builtin_nontemporal_load((const short8*)&eabf[(size_t)en * 64 + hi * 8]);
            b1_cur = __builtin_nontemporal_load((const short8*)&eabf[(size_t)en * 64 + 32 + hi * 8]);
        }

        const unsigned short* pdrow = Pbf + (size_t)d * 512 + hi * 8;
        const unsigned short* psrow = Pbf + (size_t)s * 512 + hi * 8;

        // ---- pass S ----
        unsigned pvp[16];
        {
            short8 pds[4], pss[4];
#pragma unroll
            for (int i = 0; i < 4; ++i) {
                pds[i] = *(const short8*)(pdrow + 256 + i * 32);
                pss[i] = *(const short8*)(psrow + 384 + i * 32);
            }
            f32x4 accS[8];
#pragma unroll
            for (int i = 0; i < 8; ++i) accS[i] = (f32x4)0.f;
#pragma unroll
            for (int nf = 0; nf < 8; ++nf) {
                short8 a0 = *(const short8*)&WecatT[(size_t)((nf + 8) * 16 + lr) * 64 + hi * 8];
                short8 a1 = *(const short8*)&WecatT[(size_t)((nf + 8) * 16 + lr) * 64 + 32 + hi * 8];
                accS[nf] = __builtin_amdgcn_mfma_f32_16x16x32_bf16(a0, b0, accS[nf], 0, 0, 0);
                accS[nf] = __builtin_amdgcn_mfma_f32_16x16x32_bf16(a1, b1, accS[nf], 0, 0, 0);
            }
#pragma unroll
            for (int j = 0; j < 16; ++j) {
                const int k0 = 2 * j, k1 = 2 * j + 1;
                float v0 = accS[k0 >> 2][k0 & 3] + bf2f((unsigned short)pds[k0 >> 3][k0 & 7])
                                                 + bf2f((unsigned short)pss[k0 >> 3][k0 & 7]);
                float v1 = accS[k1 >> 2][k1 & 3] + bf2f((unsigned short)pds[k1 >> 3][k1 & 7])
                                                 + bf2f((unsigned short)pss[k1 >> 3][k1 & 7]);
                pvp[j] = pack2(v0, v1);
            }
        }

        // ---- pass F ----
        {
            short8 pdf[4], psf[4];
#pragma unroll
            for (int i = 0; i < 4; ++i) {
                pdf[i] = *(const short8*)(pdrow + i * 32);
                psf[i] = *(const short8*)(psrow + 128 + i * 32);
            }
            f32x4 accF[8];
#pragma unroll
            for (int i = 0; i < 8; ++i) accF[i] = (f32x4)0.f;
#pragma unroll
            for (int nf = 0; nf < 8; ++nf) {
                short8 a0 = *(const short8*)&WecatT[(size_t)(nf * 16 + lr) * 64 + hi * 8];
                short8 a1 = *(const short8*)&WecatT[(size_t)(nf * 16 + lr) * 64 + 32 + hi * 8];
                accF[nf] = __builtin_amdgcn_mfma_f32_16x16x32_bf16(a0, b0, accF[nf], 0, 0, 0);
                accF[nf] = __builtin_amdgcn_mfma_f32_16x16x32_bf16(a1, b1, accF[nf], 0, 0, 0);
            }
#pragma unroll
            for (int nf = 0; nf < 8; ++nf) {
                f32x4 m;
#pragma unroll
                for (int r = 0; r < 4; ++r) {
                    const int q = nf * 4 + r;
                    float pf = accF[nf][r] + bf2f((unsigned short)pdf[q >> 3][q & 7])
                                           + bf2f((unsigned short)psf[q >> 3][q & 7]);
                    unsigned pw = pvp[q >> 1];
                    float pv = (q & 1) ? __builtin_bit_cast(float, pw & 0xFFFF0000u)
                                       : bf2f((unsigned short)(pw & 0xFFFFu));
                    float sig = 1.f / (1.f + __expf(-pf));
                    float tt = __expf(-fabsf(pv));
                    float sp = fmaxf(pv, 0.f) + __logf(1.f + tt);
                    m[r] = sig * sp;
                }
                *(f32x4*)&mlds[w][lr][hi * 32 + nf * 4] = m;
            }
        }
        // no barrier: wave-internal LDS ordering (lgkmcnt)

        // ---- phase 2 ----
        {
#pragma unroll 4
            for (int ee = 0; ee < 16; ++ee) {
                const int j = jbase + ee;
                run0 += mlds[w][ee][lane];
                run1 += mlds[w][ee][lane + 64];
                int de = dlds[j + 1];
                int dnext = dlds[j + 2];
                if (de != dnext) {
                    if (startsInside) {
                        agg[(size_t)de * FD + fc0] = run0;
                        agg[(size_t)de * FD + fc1] = run1;
                    } else {
                        unsafeAtomicAdd(&agg[(size_t)de * FD + fc0], run0);
                        unsafeAtomicAdd(&agg[(size_t)de * FD + fc1], run1);
                    }
                    run0 = 0.f; run1 = 0.f;
                    startsInside = true;
                }
            }
        }
    }
    if (run0 != 0.f || run1 != 0.f) {
        unsafeAtomicAdd(&agg[(size_t)dlds[wspan + 64] * FD + fc0], run0);
        unsafeAtomicAdd(&agg[(size_t)dlds[wspan + 64] * FD + fc1], run1);
    }
}

// -------- BatchNorm stats over N rows (LDS pair-reduce, then one atomic per col) --------
__global__ __launch_bounds__(256) void bn_stats_kernel(
    const float* __restrict__ agg, float* __restrict__ stats)
{
    __shared__ float sl[256], sql[256];
    const int tid = threadIdx.x;
    const int f = tid & 127;
    float s = 0.f, sq = 0.f;
    for (int row = blockIdx.x * 2 + (tid >> 7); row < N_NODES; row += gridDim.x * 2) {
        float v = agg[(size_t)row * FD + f];
        s += v; sq += v * v;
    }
    sl[tid] = s; sql[tid] = sq;
    __syncthreads();
    if (tid < 128) {
        unsafeAtomicAdd(&stats[f], sl[tid] + sl[tid + 128]);
        unsafeAtomicAdd(&stats[128 + f], sql[tid] + sql[tid + 128]);
    }
}

// -------- h = relu(h + BN(agg)); write fp32 + bf16; atomicMax per-graph --------
__global__ __launch_bounds__(256) void bn_update_kernel(
    float* __restrict__ h, unsigned short* __restrict__ hbf,
    const float* __restrict__ agg,
    const float* __restrict__ stats, const float* __restrict__ g,
    const float* __restrict__ b, const int* __restrict__ batch,
    float* __restrict__ gmax)
{
    const int tid = threadIdx.x;
    const int row = blockIdx.x * 2 + (tid >> 7);
    if (row >= N_NODES) return;
    const int f = tid & 127;
    const float inv = 1.f / (float)N_NODES;
    float mu = stats[f] * inv;
    float var = stats[128 + f] * inv - mu * mu;
    float rs = rsqrtf(var + 1e-5f);
    size_t idx = (size_t)row * FD + f;
    float v = h[idx] + (agg[idx] - mu) * rs * g[f] + b[f];
    v = fmaxf(v, 0.f);
    h[idx] = v;
    hbf[idx] = f2bf(v);
    atomicMax((unsigned*)&gmax[batch[row] * FD + f], __float_as_uint(v));
}

// -------- final layer: gmax only (h/hbf dead afterwards) --------
__global__ __launch_bounds__(256) void bn_gmax_kernel(
    const float* __restrict__ h, const float* __restrict__ agg,
    const float* __restrict__ stats, const float* __restrict__ g,
    const float* __restrict__ b, const int* __restrict__ batch,
    float* __restrict__ gmax)
{
    const int tid = threadIdx.x;
    const int row = blockIdx.x * 2 + (tid >> 7);
    if (row >= N_NODES) return;
    const int f = tid & 127;
    const float inv = 1.f / (float)N_NODES;
    float mu = stats[f] * inv;
    float var = stats[128 + f] * inv - mu * mu;
    float rs = rsqrtf(var + 1e-5f);
    size_t idx = (size_t)row * FD + f;
    float v = h[idx] + (agg[idx] - mu) * rs * g[f] + b[f];
    v = fmaxf(v, 0.f);
    atomicMax((unsigned*)&gmax[batch[row] * FD + f], __float_as_uint(v));
}

__global__ __launch_bounds__(256) void gf_acc_kernel(float* __restrict__ gf, const float* __restrict__ gmax)
{
    int i = blockIdx.x * 256 + threadIdx.x;
    gf[i] += gmax[i];
}

// -------- head --------
__global__ __launch_bounds__(128) void head_y_kernel(
    const float* __restrict__ gf, const float* __restrict__ w1,
    const float* __restrict__ b1, float* __restrict__ y)
{
    __shared__ float row[128];
    int g = blockIdx.x, j = threadIdx.x;
    row[j] = gf[g * FD + j];
    __syncthreads();
    float acc = b1[j];
    for (int k = 0; k < FD; ++k) acc = fmaf(row[k], w1[k * FD + j], acc);
    y[g * FD + j] = acc;
}

__global__ __launch_bounds__(128) void head_stats_kernel(
    const float* __restrict__ y, float* __restrict__ hstat)
{
    int f = threadIdx.x;
    float s = 0.f, sq = 0.f;
    for (int g = 0; g < NG; ++g) { float v = y[g * FD + f]; s += v; sq += v * v; }
    float mu = s / (float)NG;
    float var = sq / (float)NG - mu * mu;
    hstat[f] = mu;
    hstat[128 + f] = rsqrtf(var + 1e-5f);
}

__global__ __launch_bounds__(128) void head_out_kernel(
    const float* __restrict__ y, const float* __restrict__ hstat,
    const float* __restrict__ bng, const float* __restrict__ bnb,
    const float* __restrict__ w2, const float* __restrict__ b2,
    float* __restrict__ out)
{
    __shared__ float part[2];
    int g = blockIdx.x, f = threadIdx.x;
    float v = (y[g * FD + f] - hstat[f]) * hstat[128 + f] * bng[f] + bnb[f];
    v = fmaxf(v, 0.f) * w2[f];
    for (int o = 32; o > 0; o >>= 1) v += __shfl_down(v, o);
    if ((f & 63) == 0) part[f >> 6] = v;
    __syncthreads();
    if (f == 0) out[g] = part[0] + part[1] + b2[0];
}

extern "C" void kernel_launch(void* const* d_in, const int* in_sizes, int n_in,
                              void* d_out, int out_size, void* d_ws, size_t ws_size,
                              hipStream_t stream)
{
    const float* x        = (const float*)d_in[0];
    const float* edge_attr= (const float*)d_in[1];
    const float* w_emb0   = (const float*)d_in[2];
    const float* w_emb1   = (const float*)d_in[3];
    const float* wf       = (const float*)d_in[4];
    const float* bf       = (const float*)d_in[5];
    const float* wsw      = (const float*)d_in[6];
    const float* bs       = (const float*)d_in[7];
    const float* bn_g     = (const float*)d_in[8];
    const float* bn_b     = (const float*)d_in[9];
    const float* w1       = (const float*)d_in[10];
    const float* b1       = (const float*)d_in[11];
    const float* bng      = (const float*)d_in[12];
    const float* bnb      = (const float*)d_in[13];
    const float* w2       = (const float*)d_in[14];
    const float* b2       = (const float*)d_in[15];
    const int*   eidx     = (const int*)d_in[16];   // [2][E]: row0=src, row1=dst
    const int*   batch    = (const int*)d_in[17];

    char* base = (char*)d_ws;
    size_t off = 0;
    auto alloc = [&](size_t bytes) -> void* {
        void* p = base + off;
        off += (bytes + 255) & ~(size_t)255;
        return p;
    };
    float*          h      = (float*)alloc((size_t)N_NODES * FD * 4);
    unsigned short* hbf    = (unsigned short*)alloc((size_t)N_NODES * FD * 2);
    unsigned short* Pbf    = (unsigned short*)alloc((size_t)N_NODES * 512 * 2);
    // agg|stats|gmax contiguous -> single per-layer memset
    float*          agg    = (float*)alloc((size_t)N_NODES * FD * 4);   // also embed tmp + sort scratch
    float*          stats  = (float*)alloc(256 * 4);
    float*          gmax   = (float*)alloc((size_t)NG * FD * 4);
    unsigned short* BcatT  = (unsigned short*)alloc((size_t)NL * 512 * 128 * 2);
    unsigned short* WecatT = (unsigned short*)alloc((size_t)NL * 256 * 64 * 2);
    float*          bcatF  = (float*)alloc((size_t)NL * 512 * 4);
    unsigned short* eabf   = (unsigned short*)alloc((size_t)N_EDGES * 64 * 2);
    int*            srcS   = (int*)alloc((size_t)N_EDGES * 4);
    int*            dstS   = (int*)alloc((size_t)N_EDGES * 4);
    unsigned short* xbf    = (unsigned short*)alloc((size_t)N_NODES * 96 * 2);
    unsigned short* w0T    = (unsigned short*)alloc((size_t)128 * 96 * 2);
    unsigned short* w1T    = (unsigned short*)alloc((size_t)128 * 128 * 2);
    float*          gf     = (float*)alloc((size_t)NG * FD * 4);
    float*          y      = (float*)alloc((size_t)NG * FD * 4);
    float*          hstat  = (float*)alloc(256 * 4);

    const size_t msetBytes = (size_t)((char*)gmax + (size_t)NG * FD * 4 - (char*)agg);

    // sort scratch overlaid on agg (dead until layer loop; all sort users complete first)
    int* perm   = (int*)agg;               // [E]
    int* counts = perm + N_EDGES;          // [N]
    int* cursor = counts + N_NODES;        // [N]
    // t0 (embed intermediate, bf16 [N][128]) also overlays agg (after ea2bf consumed perm)
    unsigned short* t0bf = (unsigned short*)agg;

    const int MB = (N_NODES + 63) / 64;  // 782

    // ---- dst-sort the edges (once, reused across layers) ----
    hipMemsetAsync(counts, 0, (size_t)N_NODES * 4, stream);
    hist_kernel<<<(N_EDGES + 255) / 256, 256, 0, stream>>>(eidx + N_EDGES, counts);
    scan_kernel<<<1, 1024, 0, stream>>>(counts, cursor);
    scatter_kernel<<<(N_EDGES + 255) / 256, 256, 0, stream>>>(eidx, cursor, perm, srcS, dstS);
    ea2bf2_kernel<<<(N_EDGES * 32) / 256, 256, 0, stream>>>(edge_attr, perm, (unsigned*)eabf);

    build_bcatT_kernel<<<(NL * 512 * 128 + 255) / 256, 256, 0, stream>>>(wf, wsw, bf, bs, BcatT, bcatF);
    build_wecat_kernel<<<(NL * 256 * 64 + 255) / 256, 256, 0, stream>>>(wf, wsw, WecatT);
    build_wemb_kernel<<<64, 256, 0, stream>>>(w_emb0, w_emb1, w0T, w1T);
    x2bf_kernel<<<(N_NODES * 96 + 255) / 256, 256, 0, stream>>>(x, xbf);

    // embedding MLP (all-bf16 GEMMs): t0 = relu(xbf@w0); h(+hbf) = t0@w1
    gemm_bbg_kernel<96, 2, 1, 0, 1><<<MB, 256, 0, stream>>>(xbf, w0T, nullptr, t0bf, nullptr, N_NODES);
    gemm_bbg_kernel<128, 2, 0, 0, 2><<<MB, 256, 0, stream>>>(t0bf, w1T, nullptr, h, hbf, N_NODES);

    hipMemsetAsync(gf, 0, (size_t)NG * FD * 4, stream);

    for (int l = 0; l < NL; ++l) {
        hipMemsetAsync(agg, 0, msetBytes, stream);   // zeros agg + stats + gmax

        // P = hbf @ BcatT[l]^T + bcatF[l]  -> bf16 [N][512], posFeat2-permuted
        gemm_bbg_kernel<128, 8, 0, 1, 1><<<MB, 256, 0, stream>>>(
            hbf, BcatT + (size_t)l * 512 * 128, bcatF + (size_t)l * 512, Pbf, nullptr, N_NODES);

        msg15_kernel<<<N_EDGES / (NW * 32), 128, 0, stream>>>(
            Pbf, eabf, WecatT + (size_t)l * 256 * 64, srcS, dstS, agg);

        bn_stats_kernel<<<256, 256, 0, stream>>>(agg, stats);
        if (l < NL - 1) {
            bn_update_kernel<<<(N_NODES + 1) / 2, 256, 0, stream>>>(
                h, hbf, agg, stats, bn_g + l * FD, bn_b + l * FD, batch, gmax);
        } else {
            bn_gmax_kernel<<<(N_NODES + 1) / 2, 256, 0, stream>>>(
                h, agg, stats, bn_g + l * FD, bn_b + l * FD, batch, gmax);
        }
        gf_acc_kernel<<<(NG * FD) / 256, 256, 0, stream>>>(gf, gmax);
    }

    head_y_kernel<<<NG, 128, 0, stream>>>(gf, w1, b1, y);
    head_stats_kernel<<<1, 128, 0, stream>>>(y, hstat);
    head_out_kernel<<<NG, 128, 0, stream>>>(y, hstat, bng, bnb, w2, b2, (float*)d_out);
}

// Round 19
// 1163.540 us; speedup vs baseline: 1.6010x; 1.0972x over previous
//
#include <hip/hip_runtime.h>
#include <hip/hip_bf16.h>

#define N_NODES 50000
#define N_EDGES 800000
#define FIN 92
#define FD 128
#define DE 50
#define NL 3
#define NG 256
#define MPAD 130
#define NW 4

typedef short short8 __attribute__((ext_vector_type(8)));
typedef float f32x4 __attribute__((ext_vector_type(4)));

__device__ __forceinline__ unsigned short f2bf(float f) {
    unsigned u = __builtin_bit_cast(unsigned, f);
    unsigned r = (u + 0x7FFFu + ((u >> 16) & 1u)) >> 16;
    return (unsigned short)r;
}
__device__ __forceinline__ float bf2f(unsigned short b) {
    unsigned u = ((unsigned)b) << 16;
    return __builtin_bit_cast(float, u);
}
__device__ __forceinline__ unsigned pack2(float a, float b) {
    return (unsigned)f2bf(a) | ((unsigned)f2bf(b) << 16);
}
// native transcendentals (guaranteed v_exp/v_log/v_rcp, no lib sequence)
__device__ __forceinline__ float nexp(float x) {
    return __builtin_amdgcn_exp2f(x * 1.4426950408889634f);
}
__device__ __forceinline__ float nlog(float x) {
    return __builtin_amdgcn_logf(x) * 0.6931471805599453f;
}
__device__ __forceinline__ float nrcp(float x) {
    return __builtin_amdgcn_rcpf(x);
}

// mlds stored-pos p (hi*32 + nf*4 + r) -> true feature  (for agg write)
__device__ __forceinline__ int posFeat(int p) {
    return ((p >> 2) & 7) * 16 + ((p >> 5) << 2) + (p & 3);
}
// P stored-pos p (i*32 + hi*8 + j) -> true feature  (line-coalesced gather layout)
__device__ __forceinline__ int posFeat2(int p) {
    int q = ((p >> 5) << 3) | (p & 7);
    return ((q >> 2) << 4) + (((p >> 3) & 3) << 2) + (q & 3);
}

// ===== unified all-bf16 MFMA GEMM: A[M][K] bf16, Bt[NT*64][K] bf16 ([n][k]) =====
template<int K, int NT, int RELU, int BIAS, int OUTMODE>
__global__ __launch_bounds__(256) void gemm_bbg_kernel(
    const unsigned short* __restrict__ Abf, const unsigned short* __restrict__ Bt,
    const float* __restrict__ bias, void* __restrict__ Cout, void* __restrict__ Cout2, int M)
{
    __shared__ short Alds[64][K + 8];
    __shared__ short Blds[64][K + 8];
    const int tid = threadIdx.x;
    const int m0 = blockIdx.x * 64;
    constexpr int SEG = K / 8;
    constexpr int Nc = NT * 64;

    for (int i = tid; i < 64 * SEG; i += 256) {
        int r = i / SEG, sg = i - r * SEG;
        int row = m0 + r;
        short8 va = (row < M) ? *(const short8*)&Abf[(size_t)row * K + sg * 8] : (short8)0;
        *(short8*)&Alds[r][sg * 8] = va;
    }

    const int wv = tid >> 6, lane = tid & 63;
    const int lr = lane & 15, lk = (lane >> 4) * 8;

    for (int nt = 0; nt < NT; ++nt) {
        __syncthreads();   // prev tile consumed (also orders A-stage at nt=0)
        for (int i = tid; i < 64 * SEG; i += 256) {
            int r = i / SEG, sg = i - r * SEG;
            *(short8*)&Blds[r][sg * 8] = *(const short8*)&Bt[(size_t)(nt * 64 + r) * K + sg * 8];
        }
        __syncthreads();

        f32x4 acc[4];
#pragma unroll
        for (int i = 0; i < 4; ++i) acc[i] = (f32x4)0.f;
#pragma unroll
        for (int k0 = 0; k0 < K; k0 += 32) {
            short8 a = *(const short8*)&Alds[wv * 16 + lr][k0 + lk];
#pragma unroll
            for (int nf = 0; nf < 4; ++nf) {
                short8 b = *(const short8*)&Blds[nf * 16 + lr][k0 + lk];
                acc[nf] = __builtin_amdgcn_mfma_f32_16x16x32_bf16(a, b, acc[nf], 0, 0, 0);
            }
        }
#pragma unroll
        for (int nf = 0; nf < 4; ++nf) {
#pragma unroll
            for (int r = 0; r < 4; ++r) {
                int row = m0 + wv * 16 + (lane >> 4) * 4 + r;
                int col = nt * 64 + nf * 16 + lr;
                if (row < M) {
                    float v = acc[nf][r];
                    if (BIAS) v += bias[col];
                    if (RELU) v = fmaxf(v, 0.f);
                    if (OUTMODE == 1) {
                        ((unsigned short*)Cout)[(size_t)row * Nc + col] = f2bf(v);
                    } else {
                        ((float*)Cout)[(size_t)row * Nc + col] = v;
                        ((unsigned short*)Cout2)[(size_t)row * Nc + col] = f2bf(v);
                    }
                }
            }
        }
    }
}

// -------- x fp32 [N][92] -> bf16 padded [N][96] --------
__global__ __launch_bounds__(256) void x2bf_kernel(
    const float* __restrict__ x, unsigned short* __restrict__ xbf)
{
    int i = blockIdx.x * 256 + threadIdx.x;
    if (i >= N_NODES * 96) return;
    int row = i / 96, k = i - row * 96;
    float v = (k < FIN) ? __builtin_nontemporal_load(&x[(size_t)row * FIN + k]) : 0.f;
    xbf[i] = f2bf(v);
}

// -------- build transposed bf16 embed weights w0T[128][96], w1T[128][128] --------
__global__ __launch_bounds__(256) void build_wemb_kernel(
    const float* __restrict__ w_emb0, const float* __restrict__ w_emb1,
    unsigned short* __restrict__ w0T, unsigned short* __restrict__ w1T)
{
    int i = blockIdx.x * 256 + threadIdx.x;
    if (i < 128 * 96) {
        int n = i / 96, k = i - n * 96;
        w0T[i] = (k < FIN) ? f2bf(w_emb0[(size_t)k * FD + n]) : 0;
    }
    if (i < 128 * 128) {
        int n = i >> 7, k = i & 127;
        w1T[i] = f2bf(w_emb1[(size_t)k * FD + n]);
    }
}

// -------- build col-PERMUTED bf16 node-proj weights BcatT[l][512][128] + bias bcatF[l][512] --
__global__ __launch_bounds__(256) void build_bcatT_kernel(
    const float* __restrict__ wf, const float* __restrict__ wsw,
    const float* __restrict__ bfb, const float* __restrict__ bsb,
    unsigned short* __restrict__ BcatT, float* __restrict__ bcatF)
{
    int i = blockIdx.x * 256 + threadIdx.x;
    if (i < NL * 512 * 128) {
        int l = i / (512 * 128);
        int r = i - l * 512 * 128;
        int n = r >> 7, k = r & 127;
        int seg = n >> 7, p = n & 127;
        int nf_ = seg * 128 + posFeat2(p);
        const float* Wm = (nf_ < 256) ? wf : wsw;
        int jj = nf_ & 255;
        int krow = (jj < 128) ? k : (128 + k);
        int col = jj & 127;
        BcatT[i] = f2bf(Wm[((size_t)l * 306 + krow) * FD + col]);
    }
    if (i < NL * 512) {
        int l = i >> 9, n = i & 511;
        int seg = n >> 7, p = n & 127;
        float v = 0.f;
        if (seg == 0) v = bfb[l * FD + posFeat2(p)];
        else if (seg == 2) v = bsb[l * FD + posFeat2(p)];
        bcatF[i] = v;
    }
}

// -------- build transposed bf16 edge-proj weights WecatT[l][256][64] --------
__global__ __launch_bounds__(256) void build_wecat_kernel(
    const float* __restrict__ wf, const float* __restrict__ wsw,
    unsigned short* __restrict__ WecatT)
{
    int i = blockIdx.x * 256 + threadIdx.x;
    if (i >= NL * 256 * 64) return;
    int l = i / (256 * 64);
    int r = i - l * 256 * 64;
    int col = r >> 6, k = r & 63;
    float v = 0.f;
    if (k < DE) {
        const float* W = (col < 128) ? wf : wsw;
        v = W[((size_t)l * 306 + 256 + k) * FD + (col & 127)];
    }
    WecatT[i] = f2bf(v);
}

// ================= dst-sorted edge permutation (counting sort) =================
__global__ __launch_bounds__(256) void hist_kernel(
    const int* __restrict__ dstIdx, int* __restrict__ counts)
{
    int e = blockIdx.x * 256 + threadIdx.x;
    if (e < N_EDGES) atomicAdd(&counts[dstIdx[e]], 1);
}

__global__ __launch_bounds__(1024) void scan_kernel(
    const int* __restrict__ counts, int* __restrict__ cursor)
{
    __shared__ int part[1024];
    const int t = threadIdx.x;
    const int CH = 49;  // 1024*49 >= 50000
    const int base = t * CH;
    int s = 0;
    for (int i = 0; i < CH; ++i) {
        int idx = base + i;
        if (idx < N_NODES) s += counts[idx];
    }
    part[t] = s;
    __syncthreads();
    int v = s;
    for (int off = 1; off < 1024; off <<= 1) {
        int add = (t >= off) ? part[t - off] : 0;
        __syncthreads();
        v += add;
        part[t] = v;
        __syncthreads();
    }
    int pre = (t == 0) ? 0 : part[t - 1];
    for (int i = 0; i < CH; ++i) {
        int idx = base + i;
        if (idx < N_NODES) {
            cursor[idx] = pre;
            pre += counts[idx];
        }
    }
}

__global__ __launch_bounds__(256) void scatter_kernel(
    const int* __restrict__ eidx, int* __restrict__ cursor,
    int* __restrict__ perm, int* __restrict__ srcS, int* __restrict__ dstS)
{
    int e = blockIdx.x * 256 + threadIdx.x;
    if (e >= N_EDGES) return;
    int d = eidx[N_EDGES + e];
    int pos = atomicAdd(&cursor[d], 1);
    perm[pos] = e;
    srcS[pos] = eidx[e];
    dstS[pos] = d;
}

// -------- edge_attr -> bf16 padded [E][64], dst-sorted; u64 loads + packed u32 stores -----
__global__ __launch_bounds__(256) void ea2bf2_kernel(
    const float* __restrict__ ea, const int* __restrict__ perm,
    unsigned* __restrict__ out)
{
    int t = blockIdx.x * 256 + threadIdx.x;   // (edge, j) with j < 32 u32-slots
    if (t >= N_EDGES * 32) return;
    int e = t >> 5, j = t & 31;
    unsigned v = 0;
    if (j < 25) {
        int pe = perm[e];
        unsigned long long u = __builtin_nontemporal_load(
            (const unsigned long long*)(ea + (size_t)pe * DE) + j);
        float lo = __builtin_bit_cast(float, (unsigned)u);
        float hi = __builtin_bit_cast(float, (unsigned)(u >> 32));
        v = pack2(lo, hi);
    }
    out[(size_t)e * 32 + j] = v;
}

// ===== msg15n: R15 zero-barrier structure + native transcendental gate =====
__global__ __launch_bounds__(128) void msg15n_kernel(
    const unsigned short* __restrict__ Pbf,     // [N][512] bf16, posFeat2-permuted per 128-seg
    const unsigned short* __restrict__ eabf,    // [E][64] bf16, dst-sorted
    const unsigned short* __restrict__ WecatT,  // [256][64] bf16 (layer offset applied)
    const int* __restrict__ srcS, const int* __restrict__ dstS,
    float* __restrict__ agg)
{
    __shared__ float mlds[2][16][MPAD];
    __shared__ int dlds[NW * 32 + 2];
    const int tid = threadIdx.x;
    const int base = blockIdx.x * (NW * 32);

    for (int i = tid; i < NW * 32 + 2; i += 128) {
        int ge = base - 1 + i;
        int v;
        if (ge < 0) v = -1;
        else if (ge >= N_EDGES) v = -2;
        else v = __builtin_nontemporal_load(&dstS[ge]);
        dlds[i] = v;
    }

    const int w = tid >> 6, lane = tid & 63;
    const int lr = lane & 15, hi = lane >> 4;
    const int wspan = w * 64;                 // wave's first edge (block-local)

    int s_cur = __builtin_nontemporal_load(&srcS[base + wspan + lr]);
    short8 b0_cur = __builtin_nontemporal_load((const short8*)&eabf[(size_t)(base + wspan + lr) * 64 + hi * 8]);
    short8 b1_cur = __builtin_nontemporal_load((const short8*)&eabf[(size_t)(base + wspan + lr) * 64 + 32 + hi * 8]);

    __syncthreads();   // dlds ready (only barrier in the kernel)

    float run0 = 0.f, run1 = 0.f;
    bool startsInside = (dlds[wspan + 1] != dlds[wspan]);
    const int fc0 = posFeat(lane);
    const int fc1 = posFeat(lane + 64);

#pragma unroll 1
    for (int wi = 0; wi < NW; ++wi) {
        const int jbase = wspan + wi * 16;
        const int d = dlds[1 + jbase + lr];
        const int s = s_cur;
        const short8 b0 = b0_cur, b1 = b1_cur;

        if (wi + 1 < NW) {
            const int en = base + jbase + 16 + lr;
            s_cur = __builtin_nontemporal_load(&srcS[en]);
            b0_cur = __builtin_nontemporal_load((const short8*)&eabf[(size_t)en * 64 + hi * 8]);
            b1_cur = __builtin_nontemporal_load((const short8*)&eabf[(size_t)en * 64 + 32 + hi * 8]);
        }

        const unsigned short* pdrow = Pbf + (size_t)d * 512 + hi * 8;
        const unsigned short* psrow = Pbf + (size_t)s * 512 + hi * 8;

        // ---- pass S ----
        unsigned pvp[16];
        {
            short8 pds[4], pss[4];
#pragma unroll
            for (int i = 0; i < 4; ++i) {
                pds[i] = *(const short8*)(pdrow + 256 + i * 32);
                pss[i] = *(const short8*)(psrow + 384 + i * 32);
            }
            f32x4 accS[8];
#pragma unroll
            for (int i = 0; i < 8; ++i) accS[i] = (f32x4)0.f;
#pragma unroll
            for (int nf = 0; nf < 8; ++nf) {
                short8 a0 = *(const short8*)&WecatT[(size_t)((nf + 8) * 16 + lr) * 64 + hi * 8];
                short8 a1 = *(const short8*)&WecatT[(size_t)((nf + 8) * 16 + lr) * 64 + 32 + hi * 8];
                accS[nf] = __builtin_amdgcn_mfma_f32_16x16x32_bf16(a0, b0, accS[nf], 0, 0, 0);
                accS[nf] = __builtin_amdgcn_mfma_f32_16x16x32_bf16(a1, b1, accS[nf], 0, 0, 0);
            }
#pragma unroll
            for (int j = 0; j < 16; ++j) {
                const int k0 = 2 * j, k1 = 2 * j + 1;
                float v0 = accS[k0 >> 2][k0 & 3] + bf2f((unsigned short)pds[k0 >> 3][k0 & 7])
                                                 + bf2f((unsigned short)pss[k0 >> 3][k0 & 7]);
                float v1 = accS[k1 >> 2][k1 & 3] + bf2f((unsigned short)pds[k1 >> 3][k1 & 7])
                                                 + bf2f((unsigned short)pss[k1 >> 3][k1 & 7]);
                pvp[j] = pack2(v0, v1);
            }
        }

        // ---- pass F (native-transcendental gate) ----
        {
            short8 pdf[4], psf[4];
#pragma unroll
            for (int i = 0; i < 4; ++i) {
                pdf[i] = *(const short8*)(pdrow + i * 32);
                psf[i] = *(const short8*)(psrow + 128 + i * 32);
            }
            f32x4 accF[8];
#pragma unroll
            for (int i = 0; i < 8; ++i) accF[i] = (f32x4)0.f;
#pragma unroll
            for (int nf = 0; nf < 8; ++nf) {
                short8 a0 = *(const short8*)&WecatT[(size_t)(nf * 16 + lr) * 64 + hi * 8];
                short8 a1 = *(const short8*)&WecatT[(size_t)(nf * 16 + lr) * 64 + 32 + hi * 8];
                accF[nf] = __builtin_amdgcn_mfma_f32_16x16x32_bf16(a0, b0, accF[nf], 0, 0, 0);
                accF[nf] = __builtin_amdgcn_mfma_f32_16x16x32_bf16(a1, b1, accF[nf], 0, 0, 0);
            }
#pragma unroll
            for (int nf = 0; nf < 8; ++nf) {
                f32x4 m;
#pragma unroll
                for (int r = 0; r < 4; ++r) {
                    const int q = nf * 4 + r;
                    float pf = accF[nf][r] + bf2f((unsigned short)pdf[q >> 3][q & 7])
                                           + bf2f((unsigned short)psf[q >> 3][q & 7]);
                    unsigned pw = pvp[q >> 1];
                    float pv = (q & 1) ? __builtin_bit_cast(float, pw & 0xFFFF0000u)
                                       : bf2f((unsigned short)(pw & 0xFFFFu));
                    float sig = nrcp(1.f + nexp(-pf));            // v_rcp + v_exp
                    float tt = nexp(-fabsf(pv));                  // v_exp
                    float sp = fmaxf(pv, 0.f) + nlog(1.f + tt);   // v_log
                    m[r] = sig * sp;
                }
                *(f32x4*)&mlds[w][lr][hi * 32 + nf * 4] = m;
            }
        }
        // no barrier: wave-internal LDS ordering (lgkmcnt)

        // ---- phase 2 ----
        {
#pragma unroll 4
            for (int ee = 0; ee < 16; ++ee) {
                const int j = jbase + ee;
                run0 += mlds[w][ee][lane];
                run1 += mlds[w][ee][lane + 64];
                int de = dlds[j + 1];
                int dnext = dlds[j + 2];
                if (de != dnext) {
                    if (startsInside) {
                        agg[(size_t)de * FD + fc0] = run0;
                        agg[(size_t)de * FD + fc1] = run1;
                    } else {
                        unsafeAtomicAdd(&agg[(size_t)de * FD + fc0], run0);
                        unsafeAtomicAdd(&agg[(size_t)de * FD + fc1], run1);
                    }
                    run0 = 0.f; run1 = 0.f;
                    startsInside = true;
                }
            }
        }
    }
    if (run0 != 0.f || run1 != 0.f) {
        unsafeAtomicAdd(&agg[(size_t)dlds[wspan + 64] * FD + fc0], run0);
        unsafeAtomicAdd(&agg[(size_t)dlds[wspan + 64] * FD + fc1], run1);
    }
}

// -------- BatchNorm stats over N rows (LDS pair-reduce, then one atomic per col) --------
__global__ __launch_bounds__(256) void bn_stats_kernel(
    const float* __restrict__ agg, float* __restrict__ stats)
{
    __shared__ float sl[256], sql[256];
    const int tid = threadIdx.x;
    const int f = tid & 127;
    float s = 0.f, sq = 0.f;
    for (int row = blockIdx.x * 2 + (tid >> 7); row < N_NODES; row += gridDim.x * 2) {
        float v = agg[(size_t)row * FD + f];
        s += v; sq += v * v;
    }
    sl[tid] = s; sql[tid] = sq;
    __syncthreads();
    if (tid < 128) {
        unsafeAtomicAdd(&stats[f], sl[tid] + sl[tid + 128]);
        unsafeAtomicAdd(&stats[128 + f], sql[tid] + sql[tid + 128]);
    }
}

// -------- h = relu(h + BN(agg)); write fp32 + bf16; atomicMax per-graph --------
__global__ __launch_bounds__(256) void bn_update_kernel(
    float* __restrict__ h, unsigned short* __restrict__ hbf,
    const float* __restrict__ agg,
    const float* __restrict__ stats, const float* __restrict__ g,
    const float* __restrict__ b, const int* __restrict__ batch,
    float* __restrict__ gmax)
{
    const int tid = threadIdx.x;
    const int row = blockIdx.x * 2 + (tid >> 7);
    if (row >= N_NODES) return;
    const int f = tid & 127;
    const float inv = 1.f / (float)N_NODES;
    float mu = stats[f] * inv;
    float var = stats[128 + f] * inv - mu * mu;
    float rs = rsqrtf(var + 1e-5f);
    size_t idx = (size_t)row * FD + f;
    float v = h[idx] + (agg[idx] - mu) * rs * g[f] + b[f];
    v = fmaxf(v, 0.f);
    h[idx] = v;
    hbf[idx] = f2bf(v);
    atomicMax((unsigned*)&gmax[batch[row] * FD + f], __float_as_uint(v));
}

// -------- final layer: gmax only (h/hbf dead afterwards) --------
__global__ __launch_bounds__(256) void bn_gmax_kernel(
    const float* __restrict__ h, const float* __restrict__ agg,
    const float* __restrict__ stats, const float* __restrict__ g,
    const float* __restrict__ b, const int* __restrict__ batch,
    float* __restrict__ gmax)
{
    const int tid = threadIdx.x;
    const int row = blockIdx.x * 2 + (tid >> 7);
    if (row >= N_NODES) return;
    const int f = tid & 127;
    const float inv = 1.f / (float)N_NODES;
    float mu = stats[f] * inv;
    float var = stats[128 + f] * inv - mu * mu;
    float rs = rsqrtf(var + 1e-5f);
    size_t idx = (size_t)row * FD + f;
    float v = h[idx] + (agg[idx] - mu) * rs * g[f] + b[f];
    v = fmaxf(v, 0.f);
    atomicMax((unsigned*)&gmax[batch[row] * FD + f], __float_as_uint(v));
}

__global__ __launch_bounds__(256) void gf_acc_kernel(float* __restrict__ gf, const float* __restrict__ gmax)
{
    int i = blockIdx.x * 256 + threadIdx.x;
    gf[i] += gmax[i];
}

// -------- head --------
__global__ __launch_bounds__(128) void head_y_kernel(
    const float* __restrict__ gf, const float* __restrict__ w1,
    const float* __restrict__ b1, float* __restrict__ y)
{
    __shared__ float row[128];
    int g = blockIdx.x, j = threadIdx.x;
    row[j] = gf[g * FD + j];
    __syncthreads();
    float acc = b1[j];
    for (int k = 0; k < FD; ++k) acc = fmaf(row[k], w1[k * FD + j], acc);
    y[g * FD + j] = acc;
}

__global__ __launch_bounds__(128) void head_stats_kernel(
    const float* __restrict__ y, float* __restrict__ hstat)
{
    int f = threadIdx.x;
    float s = 0.f, sq = 0.f;
    for (int g = 0; g < NG; ++g) { float v = y[g * FD + f]; s += v; sq += v * v; }
    float mu = s / (float)NG;
    float var = sq / (float)NG - mu * mu;
    hstat[f] = mu;
    hstat[128 + f] = rsqrtf(var + 1e-5f);
}

__global__ __launch_bounds__(128) void head_out_kernel(
    const float* __restrict__ y, const float* __restrict__ hstat,
    const float* __restrict__ bng, const float* __restrict__ bnb,
    const float* __restrict__ w2, const float* __restrict__ b2,
    float* __restrict__ out)
{
    __shared__ float part[2];
    int g = blockIdx.x, f = threadIdx.x;
    float v = (y[g * FD + f] - hstat[f]) * hstat[128 + f] * bng[f] + bnb[f];
    v = fmaxf(v, 0.f) * w2[f];
    for (int o = 32; o > 0; o >>= 1) v += __shfl_down(v, o);
    if ((f & 63) == 0) part[f >> 6] = v;
    __syncthreads();
    if (f == 0) out[g] = part[0] + part[1] + b2[0];
}

extern "C" void kernel_launch(void* const* d_in, const int* in_sizes, int n_in,
                              void* d_out, int out_size, void* d_ws, size_t ws_size,
                              hipStream_t stream)
{
    const float* x        = (const float*)d_in[0];
    const float* edge_attr= (const float*)d_in[1];
    const float* w_emb0   = (const float*)d_in[2];
    const float* w_emb1   = (const float*)d_in[3];
    const float* wf       = (const float*)d_in[4];
    const float* bf       = (const float*)d_in[5];
    const float* wsw      = (const float*)d_in[6];
    const float* bs       = (const float*)d_in[7];
    const float* bn_g     = (const float*)d_in[8];
    const float* bn_b     = (const float*)d_in[9];
    const float* w1       = (const float*)d_in[10];
    const float* b1       = (const float*)d_in[11];
    const float* bng      = (const float*)d_in[12];
    const float* bnb      = (const float*)d_in[13];
    const float* w2       = (const float*)d_in[14];
    const float* b2       = (const float*)d_in[15];
    const int*   eidx     = (const int*)d_in[16];   // [2][E]: row0=src, row1=dst
    const int*   batch    = (const int*)d_in[17];

    char* base = (char*)d_ws;
    size_t off = 0;
    auto alloc = [&](size_t bytes) -> void* {
        void* p = base + off;
        off += (bytes + 255) & ~(size_t)255;
        return p;
    };
    float*          h      = (float*)alloc((size_t)N_NODES * FD * 4);
    unsigned short* hbf    = (unsigned short*)alloc((size_t)N_NODES * FD * 2);
    unsigned short* Pbf    = (unsigned short*)alloc((size_t)N_NODES * 512 * 2);
    // agg|stats|gmax contiguous -> single per-layer memset
    float*          agg    = (float*)alloc((size_t)N_NODES * FD * 4);   // also embed tmp + sort scratch
    float*          stats  = (float*)alloc(256 * 4);
    float*          gmax   = (float*)alloc((size_t)NG * FD * 4);
    unsigned short* BcatT  = (unsigned short*)alloc((size_t)NL * 512 * 128 * 2);
    unsigned short* WecatT = (unsigned short*)alloc((size_t)NL * 256 * 64 * 2);
    float*          bcatF  = (float*)alloc((size_t)NL * 512 * 4);
    unsigned short* eabf   = (unsigned short*)alloc((size_t)N_EDGES * 64 * 2);
    int*            srcS   = (int*)alloc((size_t)N_EDGES * 4);
    int*            dstS   = (int*)alloc((size_t)N_EDGES * 4);
    unsigned short* xbf    = (unsigned short*)alloc((size_t)N_NODES * 96 * 2);
    unsigned short* w0T    = (unsigned short*)alloc((size_t)128 * 96 * 2);
    unsigned short* w1T    = (unsigned short*)alloc((size_t)128 * 128 * 2);
    float*          gf     = (float*)alloc((size_t)NG * FD * 4);
    float*          y      = (float*)alloc((size_t)NG * FD * 4);
    float*          hstat  = (float*)alloc(256 * 4);

    const size_t msetBytes = (size_t)((char*)gmax + (size_t)NG * FD * 4 - (char*)agg);

    // sort scratch overlaid on agg (dead until layer loop; all sort users complete first)
    int* perm   = (int*)agg;               // [E]
    int* counts = perm + N_EDGES;          // [N]
    int* cursor = counts + N_NODES;        // [N]
    // t0 (embed intermediate, bf16 [N][128]) also overlays agg (after ea2bf consumed perm)
    unsigned short* t0bf = (unsigned short*)agg;

    const int MB = (N_NODES + 63) / 64;  // 782

    // ---- dst-sort the edges (once, reused across layers) ----
    hipMemsetAsync(counts, 0, (size_t)N_NODES * 4, stream);
    hist_kernel<<<(N_EDGES + 255) / 256, 256, 0, stream>>>(eidx + N_EDGES, counts);
    scan_kernel<<<1, 1024, 0, stream>>>(counts, cursor);
    scatter_kernel<<<(N_EDGES + 255) / 256, 256, 0, stream>>>(eidx, cursor, perm, srcS, dstS);
    ea2bf2_kernel<<<(N_EDGES * 32) / 256, 256, 0, stream>>>(edge_attr, perm, (unsigned*)eabf);

    build_bcatT_kernel<<<(NL * 512 * 128 + 255) / 256, 256, 0, stream>>>(wf, wsw, bf, bs, BcatT, bcatF);
    build_wecat_kernel<<<(NL * 256 * 64 + 255) / 256, 256, 0, stream>>>(wf, wsw, WecatT);
    build_wemb_kernel<<<64, 256, 0, stream>>>(w_emb0, w_emb1, w0T, w1T);
    x2bf_kernel<<<(N_NODES * 96 + 255) / 256, 256, 0, stream>>>(x, xbf);

    // embedding MLP (all-bf16 GEMMs): t0 = relu(xbf@w0); h(+hbf) = t0@w1
    gemm_bbg_kernel<96, 2, 1, 0, 1><<<MB, 256, 0, stream>>>(xbf, w0T, nullptr, t0bf, nullptr, N_NODES);
    gemm_bbg_kernel<128, 2, 0, 0, 2><<<MB, 256, 0, stream>>>(t0bf, w1T, nullptr, h, hbf, N_NODES);

    hipMemsetAsync(gf, 0, (size_t)NG * FD * 4, stream);

    for (int l = 0; l < NL; ++l) {
        hipMemsetAsync(agg, 0, msetBytes, stream);   // zeros agg + stats + gmax

        // P = hbf @ BcatT[l]^T + bcatF[l]  -> bf16 [N][512], posFeat2-permuted
        gemm_bbg_kernel<128, 8, 0, 1, 1><<<MB, 256, 0, stream>>>(
            hbf, BcatT + (size_t)l * 512 * 128, bcatF + (size_t)l * 512, Pbf, nullptr, N_NODES);

        msg15n_kernel<<<N_EDGES / (NW * 32), 128, 0, stream>>>(
            Pbf, eabf, WecatT + (size_t)l * 256 * 64, srcS, dstS, agg);

        bn_stats_kernel<<<256, 256, 0, stream>>>(agg, stats);
        if (l < NL - 1) {
            bn_update_kernel<<<(N_NODES + 1) / 2, 256, 0, stream>>>(
                h, hbf, agg, stats, bn_g + l * FD, bn_b + l * FD, batch, gmax);
        } else {
            bn_gmax_kernel<<<(N_NODES + 1) / 2, 256, 0, stream>>>(
                h, agg, stats, bn_g + l * FD, bn_b + l * FD, batch, gmax);
        }
        gf_acc_kernel<<<(NG * FD) / 256, 256, 0, stream>>>(gf, gmax);
    }

    head_y_kernel<<<NG, 128, 0, stream>>>(gf, w1, b1, y);
    head_stats_kernel<<<1, 128, 0, stream>>>(y, hstat);
    head_out_kernel<<<NG, 128, 0, stream>>>(y, hstat, bng, bnb, w2, b2, (float*)d_out);
}

// Round 20
// 1139.997 us; speedup vs baseline: 1.6341x; 1.0207x over previous
//
#include <hip/hip_runtime.h>
#include <hip/hip_bf16.h>

#define N_NODES 50000
#define N_EDGES 800000
#define FIN 92
#define FD 128
#define DE 50
#define NL 3
#define NG 256
#define MPAD 130
#define NW 8
#define WEDGE (NW * 16)      // 128 edges per wave
#define BEDGE (2 * WEDGE)    // 256 edges per block

typedef short short8 __attribute__((ext_vector_type(8)));
typedef float f32x4 __attribute__((ext_vector_type(4)));

__device__ __forceinline__ unsigned short f2bf(float f) {
    unsigned u = __builtin_bit_cast(unsigned, f);
    unsigned r = (u + 0x7FFFu + ((u >> 16) & 1u)) >> 16;
    return (unsigned short)r;
}
__device__ __forceinline__ float bf2f(unsigned short b) {
    unsigned u = ((unsigned)b) << 16;
    return __builtin_bit_cast(float, u);
}
__device__ __forceinline__ unsigned pack2(float a, float b) {
    return (unsigned)f2bf(a) | ((unsigned)f2bf(b) << 16);
}
// native transcendentals (guaranteed v_exp/v_log/v_rcp, no lib sequence)
__device__ __forceinline__ float nexp(float x) {
    return __builtin_amdgcn_exp2f(x * 1.4426950408889634f);
}
__device__ __forceinline__ float nlog(float x) {
    return __builtin_amdgcn_logf(x) * 0.6931471805599453f;
}
__device__ __forceinline__ float nrcp(float x) {
    return __builtin_amdgcn_rcpf(x);
}

// mlds stored-pos p (hi*32 + nf*4 + r) -> true feature  (for agg write)
__device__ __forceinline__ int posFeat(int p) {
    return ((p >> 2) & 7) * 16 + ((p >> 5) << 2) + (p & 3);
}
// P stored-pos p (i*32 + hi*8 + j) -> true feature  (line-coalesced gather layout)
__device__ __forceinline__ int posFeat2(int p) {
    int q = ((p >> 5) << 3) | (p & 7);
    return ((q >> 2) << 4) + (((p >> 3) & 3) << 2) + (q & 3);
}

// ===== unified all-bf16 MFMA GEMM: A[M][K] bf16, Bt[NT*64][K] bf16 ([n][k]) =====
template<int K, int NT, int RELU, int BIAS, int OUTMODE>
__global__ __launch_bounds__(256) void gemm_bbg_kernel(
    const unsigned short* __restrict__ Abf, const unsigned short* __restrict__ Bt,
    const float* __restrict__ bias, void* __restrict__ Cout, void* __restrict__ Cout2, int M)
{
    __shared__ short Alds[64][K + 8];
    __shared__ short Blds[64][K + 8];
    const int tid = threadIdx.x;
    const int m0 = blockIdx.x * 64;
    constexpr int SEG = K / 8;
    constexpr int Nc = NT * 64;

    for (int i = tid; i < 64 * SEG; i += 256) {
        int r = i / SEG, sg = i - r * SEG;
        int row = m0 + r;
        short8 va = (row < M) ? *(const short8*)&Abf[(size_t)row * K + sg * 8] : (short8)0;
        *(short8*)&Alds[r][sg * 8] = va;
    }

    const int wv = tid >> 6, lane = tid & 63;
    const int lr = lane & 15, lk = (lane >> 4) * 8;

    for (int nt = 0; nt < NT; ++nt) {
        __syncthreads();   // prev tile consumed (also orders A-stage at nt=0)
        for (int i = tid; i < 64 * SEG; i += 256) {
            int r = i / SEG, sg = i - r * SEG;
            *(short8*)&Blds[r][sg * 8] = *(const short8*)&Bt[(size_t)(nt * 64 + r) * K + sg * 8];
        }
        __syncthreads();

        f32x4 acc[4];
#pragma unroll
        for (int i = 0; i < 4; ++i) acc[i] = (f32x4)0.f;
#pragma unroll
        for (int k0 = 0; k0 < K; k0 += 32) {
            short8 a = *(const short8*)&Alds[wv * 16 + lr][k0 + lk];
#pragma unroll
            for (int nf = 0; nf < 4; ++nf) {
                short8 b = *(const short8*)&Blds[nf * 16 + lr][k0 + lk];
                acc[nf] = __builtin_amdgcn_mfma_f32_16x16x32_bf16(a, b, acc[nf], 0, 0, 0);
            }
        }
#pragma unroll
        for (int nf = 0; nf < 4; ++nf) {
#pragma unroll
            for (int r = 0; r < 4; ++r) {
                int row = m0 + wv * 16 + (lane >> 4) * 4 + r;
                int col = nt * 64 + nf * 16 + lr;
                if (row < M) {
                    float v = acc[nf][r];
                    if (BIAS) v += bias[col];
                    if (RELU) v = fmaxf(v, 0.f);
                    if (OUTMODE == 1) {
                        ((unsigned short*)Cout)[(size_t)row * Nc + col] = f2bf(v);
                    } else {
                        ((float*)Cout)[(size_t)row * Nc + col] = v;
                        ((unsigned short*)Cout2)[(size_t)row * Nc + col] = f2bf(v);
                    }
                }
            }
        }
    }
}

// -------- x fp32 [N][92] -> bf16 padded [N][96] --------
__global__ __launch_bounds__(256) void x2bf_kernel(
    const float* __restrict__ x, unsigned short* __restrict__ xbf)
{
    int i = blockIdx.x * 256 + threadIdx.x;
    if (i >= N_NODES * 96) return;
    int row = i / 96, k = i - row * 96;
    float v = (k < FIN) ? __builtin_nontemporal_load(&x[(size_t)row * FIN + k]) : 0.f;
    xbf[i] = f2bf(v);
}

// -------- build transposed bf16 embed weights w0T[128][96], w1T[128][128] --------
__global__ __launch_bounds__(256) void build_wemb_kernel(
    const float* __restrict__ w_emb0, const float* __restrict__ w_emb1,
    unsigned short* __restrict__ w0T, unsigned short* __restrict__ w1T)
{
    int i = blockIdx.x * 256 + threadIdx.x;
    if (i < 128 * 96) {
        int n = i / 96, k = i - n * 96;
        w0T[i] = (k < FIN) ? f2bf(w_emb0[(size_t)k * FD + n]) : 0;
    }
    if (i < 128 * 128) {
        int n = i >> 7, k = i & 127;
        w1T[i] = f2bf(w_emb1[(size_t)k * FD + n]);
    }
}

// -------- build col-PERMUTED bf16 node-proj weights BcatT[l][512][128] + bias bcatF[l][512] --
__global__ __launch_bounds__(256) void build_bcatT_kernel(
    const float* __restrict__ wf, const float* __restrict__ wsw,
    const float* __restrict__ bfb, const float* __restrict__ bsb,
    unsigned short* __restrict__ BcatT, float* __restrict__ bcatF)
{
    int i = blockIdx.x * 256 + threadIdx.x;
    if (i < NL * 512 * 128) {
        int l = i / (512 * 128);
        int r = i - l * 512 * 128;
        int n = r >> 7, k = r & 127;
        int seg = n >> 7, p = n & 127;
        int nf_ = seg * 128 + posFeat2(p);
        const float* Wm = (nf_ < 256) ? wf : wsw;
        int jj = nf_ & 255;
        int krow = (jj < 128) ? k : (128 + k);
        int col = jj & 127;
        BcatT[i] = f2bf(Wm[((size_t)l * 306 + krow) * FD + col]);
    }
    if (i < NL * 512) {
        int l = i >> 9, n = i & 511;
        int seg = n >> 7, p = n & 127;
        float v = 0.f;
        if (seg == 0) v = bfb[l * FD + posFeat2(p)];
        else if (seg == 2) v = bsb[l * FD + posFeat2(p)];
        bcatF[i] = v;
    }
}

// -------- build transposed bf16 edge-proj weights WecatT[l][256][64] --------
__global__ __launch_bounds__(256) void build_wecat_kernel(
    const float* __restrict__ wf, const float* __restrict__ wsw,
    unsigned short* __restrict__ WecatT)
{
    int i = blockIdx.x * 256 + threadIdx.x;
    if (i >= NL * 256 * 64) return;
    int l = i / (256 * 64);
    int r = i - l * 256 * 64;
    int col = r >> 6, k = r & 63;
    float v = 0.f;
    if (k < DE) {
        const float* W = (col < 128) ? wf : wsw;
        v = W[((size_t)l * 306 + 256 + k) * FD + (col & 127)];
    }
    WecatT[i] = f2bf(v);
}

// ================= dst-sorted edge permutation (counting sort) =================
__global__ __launch_bounds__(256) void hist_kernel(
    const int* __restrict__ dstIdx, int* __restrict__ counts)
{
    int e = blockIdx.x * 256 + threadIdx.x;
    if (e < N_EDGES) atomicAdd(&counts[dstIdx[e]], 1);
}

__global__ __launch_bounds__(1024) void scan_kernel(
    const int* __restrict__ counts, int* __restrict__ cursor)
{
    __shared__ int part[1024];
    const int t = threadIdx.x;
    const int CH = 49;  // 1024*49 >= 50000
    const int base = t * CH;
    int s = 0;
    for (int i = 0; i < CH; ++i) {
        int idx = base + i;
        if (idx < N_NODES) s += counts[idx];
    }
    part[t] = s;
    __syncthreads();
    int v = s;
    for (int off = 1; off < 1024; off <<= 1) {
        int add = (t >= off) ? part[t - off] : 0;
        __syncthreads();
        v += add;
        part[t] = v;
        __syncthreads();
    }
    int pre = (t == 0) ? 0 : part[t - 1];
    for (int i = 0; i < CH; ++i) {
        int idx = base + i;
        if (idx < N_NODES) {
            cursor[idx] = pre;
            pre += counts[idx];
        }
    }
}

__global__ __launch_bounds__(256) void scatter_kernel(
    const int* __restrict__ eidx, int* __restrict__ cursor,
    int* __restrict__ perm, int* __restrict__ srcS, int* __restrict__ dstS)
{
    int e = blockIdx.x * 256 + threadIdx.x;
    if (e >= N_EDGES) return;
    int d = eidx[N_EDGES + e];
    int pos = atomicAdd(&cursor[d], 1);
    perm[pos] = e;
    srcS[pos] = eidx[e];
    dstS[pos] = d;
}

// -------- edge_attr -> bf16 padded [E][64], dst-sorted; u64 loads + packed u32 stores -----
__global__ __launch_bounds__(256) void ea2bf2_kernel(
    const float* __restrict__ ea, const int* __restrict__ perm,
    unsigned* __restrict__ out)
{
    int t = blockIdx.x * 256 + threadIdx.x;   // (edge, j) with j < 32 u32-slots
    if (t >= N_EDGES * 32) return;
    int e = t >> 5, j = t & 31;
    unsigned v = 0;
    if (j < 25) {
        int pe = perm[e];
        unsigned long long u = __builtin_nontemporal_load(
            (const unsigned long long*)(ea + (size_t)pe * DE) + j);
        float lo = __builtin_bit_cast(float, (unsigned)u);
        float hi = __builtin_bit_cast(float, (unsigned)(u >> 32));
        v = pack2(lo, hi);
    }
    out[(size_t)e * 32 + j] = v;
}

// ===== msg15n8: zero-barrier wave-independent + native transcendentals, NW=8 =====
// Wave w owns edges [base + w*WEDGE, base + (w+1)*WEDGE) as NW windows of 16.
__global__ __launch_bounds__(128) void msg15n8_kernel(
    const unsigned short* __restrict__ Pbf,     // [N][512] bf16, posFeat2-permuted per 128-seg
    const unsigned short* __restrict__ eabf,    // [E][64] bf16, dst-sorted
    const unsigned short* __restrict__ WecatT,  // [256][64] bf16 (layer offset applied)
    const int* __restrict__ srcS, const int* __restrict__ dstS,
    float* __restrict__ agg)
{
    __shared__ float mlds[2][16][MPAD];
    __shared__ int dlds[BEDGE + 2];
    const int tid = threadIdx.x;
    const int base = blockIdx.x * BEDGE;

    for (int i = tid; i < BEDGE + 2; i += 128) {
        int ge = base - 1 + i;
        int v;
        if (ge < 0) v = -1;
        else if (ge >= N_EDGES) v = -2;
        else v = __builtin_nontemporal_load(&dstS[ge]);
        dlds[i] = v;
    }

    const int w = tid >> 6, lane = tid & 63;
    const int lr = lane & 15, hi = lane >> 4;
    const int wspan = w * WEDGE;              // wave's first edge (block-local)

    int s_cur = __builtin_nontemporal_load(&srcS[base + wspan + lr]);
    short8 b0_cur = __builtin_nontemporal_load((const short8*)&eabf[(size_t)(base + wspan + lr) * 64 + hi * 8]);
    short8 b1_cur = __builtin_nontemporal_load((const short8*)&eabf[(size_t)(base + wspan + lr) * 64 + 32 + hi * 8]);

    __syncthreads();   // dlds ready (only barrier in the kernel)

    float run0 = 0.f, run1 = 0.f;
    bool startsInside = (dlds[wspan + 1] != dlds[wspan]);
    const int fc0 = posFeat(lane);
    const int fc1 = posFeat(lane + 64);

#pragma unroll 1
    for (int wi = 0; wi < NW; ++wi) {
        const int jbase = wspan + wi * 16;
        const int d = dlds[1 + jbase + lr];
        const int s = s_cur;
        const short8 b0 = b0_cur, b1 = b1_cur;

        if (wi + 1 < NW) {
            const int en = base + jbase + 16 + lr;
            s_cur = __builtin_nontemporal_load(&srcS[en]);
            b0_cur = __builtin_nontemporal_load((const short8*)&eabf[(size_t)en * 64 + hi * 8]);
            b1_cur = __builtin_nontemporal_load((const short8*)&eabf[(size_t)en * 64 + 32 + hi * 8]);
        }

        const unsigned short* pdrow = Pbf + (size_t)d * 512 + hi * 8;
        const unsigned short* psrow = Pbf + (size_t)s * 512 + hi * 8;

        // ---- pass S ----
        unsigned pvp[16];
        {
            short8 pds[4], pss[4];
#pragma unroll
            for (int i = 0; i < 4; ++i) {
                pds[i] = *(const short8*)(pdrow + 256 + i * 32);
                pss[i] = *(const short8*)(psrow + 384 + i * 32);
            }
            f32x4 accS[8];
#pragma unroll
            for (int i = 0; i < 8; ++i) accS[i] = (f32x4)0.f;
#pragma unroll
            for (int nf = 0; nf < 8; ++nf) {
                short8 a0 = *(const short8*)&WecatT[(size_t)((nf + 8) * 16 + lr) * 64 + hi * 8];
                short8 a1 = *(const short8*)&WecatT[(size_t)((nf + 8) * 16 + lr) * 64 + 32 + hi * 8];
                accS[nf] = __builtin_amdgcn_mfma_f32_16x16x32_bf16(a0, b0, accS[nf], 0, 0, 0);
                accS[nf] = __builtin_amdgcn_mfma_f32_16x16x32_bf16(a1, b1, accS[nf], 0, 0, 0);
            }
#pragma unroll
            for (int j = 0; j < 16; ++j) {
                const int k0 = 2 * j, k1 = 2 * j + 1;
                float v0 = accS[k0 >> 2][k0 & 3] + bf2f((unsigned short)pds[k0 >> 3][k0 & 7])
                                                 + bf2f((unsigned short)pss[k0 >> 3][k0 & 7]);
                float v1 = accS[k1 >> 2][k1 & 3] + bf2f((unsigned short)pds[k1 >> 3][k1 & 7])
                                                 + bf2f((unsigned short)pss[k1 >> 3][k1 & 7]);
                pvp[j] = pack2(v0, v1);
            }
        }

        // ---- pass F (native-transcendental gate) ----
        {
            short8 pdf[4], psf[4];
#pragma unroll
            for (int i = 0; i < 4; ++i) {
                pdf[i] = *(const short8*)(pdrow + i * 32);
                psf[i] = *(const short8*)(psrow + 128 + i * 32);
            }
            f32x4 accF[8];
#pragma unroll
            for (int i = 0; i < 8; ++i) accF[i] = (f32x4)0.f;
#pragma unroll
            for (int nf = 0; nf < 8; ++nf) {
                short8 a0 = *(const short8*)&WecatT[(size_t)(nf * 16 + lr) * 64 + hi * 8];
                short8 a1 = *(const short8*)&WecatT[(size_t)(nf * 16 + lr) * 64 + 32 + hi * 8];
                accF[nf] = __builtin_amdgcn_mfma_f32_16x16x32_bf16(a0, b0, accF[nf], 0, 0, 0);
                accF[nf] = __builtin_amdgcn_mfma_f32_16x16x32_bf16(a1, b1, accF[nf], 0, 0, 0);
            }
#pragma unroll
            for (int nf = 0; nf < 8; ++nf) {
                f32x4 m;
#pragma unroll
                for (int r = 0; r < 4; ++r) {
                    const int q = nf * 4 + r;
                    float pf = accF[nf][r] + bf2f((unsigned short)pdf[q >> 3][q & 7])
                                           + bf2f((unsigned short)psf[q >> 3][q & 7]);
                    unsigned pw = pvp[q >> 1];
                    float pv = (q & 1) ? __builtin_bit_cast(float, pw & 0xFFFF0000u)
                                       : bf2f((unsigned short)(pw & 0xFFFFu));
                    float sig = nrcp(1.f + nexp(-pf));            // v_rcp + v_exp
                    float tt = nexp(-fabsf(pv));                  // v_exp
                    float sp = fmaxf(pv, 0.f) + nlog(1.f + tt);   // v_log
                    m[r] = sig * sp;
                }
                *(f32x4*)&mlds[w][lr][hi * 32 + nf * 4] = m;
            }
        }
        // no barrier: wave-internal LDS ordering (lgkmcnt)

        // ---- phase 2 ----
        {
#pragma unroll 4
            for (int ee = 0; ee < 16; ++ee) {
                const int j = jbase + ee;
                run0 += mlds[w][ee][lane];
                run1 += mlds[w][ee][lane + 64];
                int de = dlds[j + 1];
                int dnext = dlds[j + 2];
                if (de != dnext) {
                    if (startsInside) {
                        agg[(size_t)de * FD + fc0] = run0;
                        agg[(size_t)de * FD + fc1] = run1;
                    } else {
                        unsafeAtomicAdd(&agg[(size_t)de * FD + fc0], run0);
                        unsafeAtomicAdd(&agg[(size_t)de * FD + fc1], run1);
                    }
                    run0 = 0.f; run1 = 0.f;
                    startsInside = true;
                }
            }
        }
    }
    if (run0 != 0.f || run1 != 0.f) {
        unsafeAtomicAdd(&agg[(size_t)dlds[wspan + WEDGE] * FD + fc0], run0);
        unsafeAtomicAdd(&agg[(size_t)dlds[wspan + WEDGE] * FD + fc1], run1);
    }
}

// -------- BatchNorm stats over N rows (LDS pair-reduce, then one atomic per col) --------
__global__ __launch_bounds__(256) void bn_stats_kernel(
    const float* __restrict__ agg, float* __restrict__ stats)
{
    __shared__ float sl[256], sql[256];
    const int tid = threadIdx.x;
    const int f = tid & 127;
    float s = 0.f, sq = 0.f;
    for (int row = blockIdx.x * 2 + (tid >> 7); row < N_NODES; row += gridDim.x * 2) {
        float v = agg[(size_t)row * FD + f];
        s += v; sq += v * v;
    }
    sl[tid] = s; sql[tid] = sq;
    __syncthreads();
    if (tid < 128) {
        unsafeAtomicAdd(&stats[f], sl[tid] + sl[tid + 128]);
        unsafeAtomicAdd(&stats[128 + f], sql[tid] + sql[tid + 128]);
    }
}

// -------- h = relu(h + BN(agg)); write fp32 + bf16; atomicMax per-graph --------
__global__ __launch_bounds__(256) void bn_update_kernel(
    float* __restrict__ h, unsigned short* __restrict__ hbf,
    const float* __restrict__ agg,
    const float* __restrict__ stats, const float* __restrict__ g,
    const float* __restrict__ b, const int* __restrict__ batch,
    float* __restrict__ gmax)
{
    const int tid = threadIdx.x;
    const int row = blockIdx.x * 2 + (tid >> 7);
    if (row >= N_NODES) return;
    const int f = tid & 127;
    const float inv = 1.f / (float)N_NODES;
    float mu = stats[f] * inv;
    float var = stats[128 + f] * inv - mu * mu;
    float rs = rsqrtf(var + 1e-5f);
    size_t idx = (size_t)row * FD + f;
    float v = h[idx] + (agg[idx] - mu) * rs * g[f] + b[f];
    v = fmaxf(v, 0.f);
    h[idx] = v;
    hbf[idx] = f2bf(v);
    atomicMax((unsigned*)&gmax[batch[row] * FD + f], __float_as_uint(v));
}

// -------- final layer: gmax only (h/hbf dead afterwards) --------
__global__ __launch_bounds__(256) void bn_gmax_kernel(
    const float* __restrict__ h, const float* __restrict__ agg,
    const float* __restrict__ stats, const float* __restrict__ g,
    const float* __restrict__ b, const int* __restrict__ batch,
    float* __restrict__ gmax)
{
    const int tid = threadIdx.x;
    const int row = blockIdx.x * 2 + (tid >> 7);
    if (row >= N_NODES) return;
    const int f = tid & 127;
    const float inv = 1.f / (float)N_NODES;
    float mu = stats[f] * inv;
    float var = stats[128 + f] * inv - mu * mu;
    float rs = rsqrtf(var + 1e-5f);
    size_t idx = (size_t)row * FD + f;
    float v = h[idx] + (agg[idx] - mu) * rs * g[f] + b[f];
    v = fmaxf(v, 0.f);
    atomicMax((unsigned*)&gmax[batch[row] * FD + f], __float_as_uint(v));
}

__global__ __launch_bounds__(256) void gf_acc_kernel(float* __restrict__ gf, const float* __restrict__ gmax)
{
    int i = blockIdx.x * 256 + threadIdx.x;
    gf[i] += gmax[i];
}

// -------- head --------
__global__ __launch_bounds__(128) void head_y_kernel(
    const float* __restrict__ gf, const float* __restrict__ w1,
    const float* __restrict__ b1, float* __restrict__ y)
{
    __shared__ float row[128];
    int g = blockIdx.x, j = threadIdx.x;
    row[j] = gf[g * FD + j];
    __syncthreads();
    float acc = b1[j];
    for (int k = 0; k < FD; ++k) acc = fmaf(row[k], w1[k * FD + j], acc);
    y[g * FD + j] = acc;
}

__global__ __launch_bounds__(128) void head_stats_kernel(
    const float* __restrict__ y, float* __restrict__ hstat)
{
    int f = threadIdx.x;
    float s = 0.f, sq = 0.f;
    for (int g = 0; g < NG; ++g) { float v = y[g * FD + f]; s += v; sq += v * v; }
    float mu = s / (float)NG;
    float var = sq / (float)NG - mu * mu;
    hstat[f] = mu;
    hstat[128 + f] = rsqrtf(var + 1e-5f);
}

__global__ __launch_bounds__(128) void head_out_kernel(
    const float* __restrict__ y, const float* __restrict__ hstat,
    const float* __restrict__ bng, const float* __restrict__ bnb,
    const float* __restrict__ w2, const float* __restrict__ b2,
    float* __restrict__ out)
{
    __shared__ float part[2];
    int g = blockIdx.x, f = threadIdx.x;
    float v = (y[g * FD + f] - hstat[f]) * hstat[128 + f] * bng[f] + bnb[f];
    v = fmaxf(v, 0.f) * w2[f];
    for (int o = 32; o > 0; o >>= 1) v += __shfl_down(v, o);
    if ((f & 63) == 0) part[f >> 6] = v;
    __syncthreads();
    if (f == 0) out[g] = part[0] + part[1] + b2[0];
}

extern "C" void kernel_launch(void* const* d_in, const int* in_sizes, int n_in,
                              void* d_out, int out_size, void* d_ws, size_t ws_size,
                              hipStream_t stream)
{
    const float* x        = (const float*)d_in[0];
    const float* edge_attr= (const float*)d_in[1];
    const float* w_emb0   = (const float*)d_in[2];
    const float* w_emb1   = (const float*)d_in[3];
    const float* wf       = (const float*)d_in[4];
    const float* bf       = (const float*)d_in[5];
    const float* wsw      = (const float*)d_in[6];
    const float* bs       = (const float*)d_in[7];
    const float* bn_g     = (const float*)d_in[8];
    const float* bn_b     = (const float*)d_in[9];
    const float* w1       = (const float*)d_in[10];
    const float* b1       = (const float*)d_in[11];
    const float* bng      = (const float*)d_in[12];
    const float* bnb      = (const float*)d_in[13];
    const float* w2       = (const float*)d_in[14];
    const float* b2       = (const float*)d_in[15];
    const int*   eidx     = (const int*)d_in[16];   // [2][E]: row0=src, row1=dst
    const int*   batch    = (const int*)d_in[17];

    char* base = (char*)d_ws;
    size_t off = 0;
    auto alloc = [&](size_t bytes) -> void* {
        void* p = base + off;
        off += (bytes + 255) & ~(size_t)255;
        return p;
    };
    float*          h      = (float*)alloc((size_t)N_NODES * FD * 4);
    unsigned short* hbf    = (unsigned short*)alloc((size_t)N_NODES * FD * 2);
    unsigned short* Pbf    = (unsigned short*)alloc((size_t)N_NODES * 512 * 2);
    // agg|stats|gmax contiguous -> single per-layer memset
    float*          agg    = (float*)alloc((size_t)N_NODES * FD * 4);   // also embed tmp + sort scratch
    float*          stats  = (float*)alloc(256 * 4);
    float*          gmax   = (float*)alloc((size_t)NG * FD * 4);
    unsigned short* BcatT  = (unsigned short*)alloc((size_t)NL * 512 * 128 * 2);
    unsigned short* WecatT = (unsigned short*)alloc((size_t)NL * 256 * 64 * 2);
    float*          bcatF  = (float*)alloc((size_t)NL * 512 * 4);
    unsigned short* eabf   = (unsigned short*)alloc((size_t)N_EDGES * 64 * 2);
    int*            srcS   = (int*)alloc((size_t)N_EDGES * 4);
    int*            dstS   = (int*)alloc((size_t)N_EDGES * 4);
    unsigned short* xbf    = (unsigned short*)alloc((size_t)N_NODES * 96 * 2);
    unsigned short* w0T    = (unsigned short*)alloc((size_t)128 * 96 * 2);
    unsigned short* w1T    = (unsigned short*)alloc((size_t)128 * 128 * 2);
    float*          gf     = (float*)alloc((size_t)NG * FD * 4);
    float*          y      = (float*)alloc((size_t)NG * FD * 4);
    float*          hstat  = (float*)alloc(256 * 4);

    const size_t msetBytes = (size_t)((char*)gmax + (size_t)NG * FD * 4 - (char*)agg);

    // sort scratch overlaid on agg (dead until layer loop; all sort users complete first)
    int* perm   = (int*)agg;               // [E]
    int* counts = perm + N_EDGES;          // [N]
    int* cursor = counts + N_NODES;        // [N]
    // t0 (embed intermediate, bf16 [N][128]) also overlays agg (after ea2bf consumed perm)
    unsigned short* t0bf = (unsigned short*)agg;

    const int MB = (N_NODES + 63) / 64;  // 782

    // ---- dst-sort the edges (once, reused across layers) ----
    hipMemsetAsync(counts, 0, (size_t)N_NODES * 4, stream);
    hist_kernel<<<(N_EDGES + 255) / 256, 256, 0, stream>>>(eidx + N_EDGES, counts);
    scan_kernel<<<1, 1024, 0, stream>>>(counts, cursor);
    scatter_kernel<<<(N_EDGES + 255) / 256, 256, 0, stream>>>(eidx, cursor, perm, srcS, dstS);
    ea2bf2_kernel<<<(N_EDGES * 32) / 256, 256, 0, stream>>>(edge_attr, perm, (unsigned*)eabf);

    build_bcatT_kernel<<<(NL * 512 * 128 + 255) / 256, 256, 0, stream>>>(wf, wsw, bf, bs, BcatT, bcatF);
    build_wecat_kernel<<<(NL * 256 * 64 + 255) / 256, 256, 0, stream>>>(wf, wsw, WecatT);
    build_wemb_kernel<<<64, 256, 0, stream>>>(w_emb0, w_emb1, w0T, w1T);
    x2bf_kernel<<<(N_NODES * 96 + 255) / 256, 256, 0, stream>>>(x, xbf);

    // embedding MLP (all-bf16 GEMMs): t0 = relu(xbf@w0); h(+hbf) = t0@w1
    gemm_bbg_kernel<96, 2, 1, 0, 1><<<MB, 256, 0, stream>>>(xbf, w0T, nullptr, t0bf, nullptr, N_NODES);
    gemm_bbg_kernel<128, 2, 0, 0, 2><<<MB, 256, 0, stream>>>(t0bf, w1T, nullptr, h, hbf, N_NODES);

    hipMemsetAsync(gf, 0, (size_t)NG * FD * 4, stream);

    for (int l = 0; l < NL; ++l) {
        hipMemsetAsync(agg, 0, msetBytes, stream);   // zeros agg + stats + gmax

        // P = hbf @ BcatT[l]^T + bcatF[l]  -> bf16 [N][512], posFeat2-permuted
        gemm_bbg_kernel<128, 8, 0, 1, 1><<<MB, 256, 0, stream>>>(
            hbf, BcatT + (size_t)l * 512 * 128, bcatF + (size_t)l * 512, Pbf, nullptr, N_NODES);

        msg15n8_kernel<<<N_EDGES / BEDGE, 128, 0, stream>>>(
            Pbf, eabf, WecatT + (size_t)l * 256 * 64, srcS, dstS, agg);

        bn_stats_kernel<<<256, 256, 0, stream>>>(agg, stats);
        if (l < NL - 1) {
            bn_update_kernel<<<(N_NODES + 1) / 2, 256, 0, stream>>>(
                h, hbf, agg, stats, bn_g + l * FD, bn_b + l * FD, batch, gmax);
        } else {
            bn_gmax_kernel<<<(N_NODES + 1) / 2, 256, 0, stream>>>(
                h, agg, stats, bn_g + l * FD, bn_b + l * FD, batch, gmax);
        }
        gf_acc_kernel<<<(NG * FD) / 256, 256, 0, stream>>>(gf, gmax);
    }

    head_y_kernel<<<NG, 128, 0, stream>>>(gf, w1, b1, y);
    head_stats_kernel<<<1, 128, 0, stream>>>(y, hstat);
    head_out_kernel<<<NG, 128, 0, stream>>>(y, hstat, bng, bnb, w2, b2, (float*)d_out);
}

// Round 21
// 1095.344 us; speedup vs baseline: 1.7007x; 1.0408x over previous
//
#include <hip/hip_runtime.h>
#include <hip/hip_bf16.h>

#define N_NODES 50000
#define N_EDGES 800000
#define FIN 92
#define FD 128
#define DE 50
#define NL 3
#define NG 256
#define MPAD 130
#define NW 10
#define WEDGE (NW * 16)      // 160 edges per wave
#define BEDGE (2 * WEDGE)    // 320 edges per block; 800000/320 = 2500 blocks

typedef short short8 __attribute__((ext_vector_type(8)));
typedef float f32x4 __attribute__((ext_vector_type(4)));

__device__ __forceinline__ unsigned short f2bf(float f) {
    unsigned u = __builtin_bit_cast(unsigned, f);
    unsigned r = (u + 0x7FFFu + ((u >> 16) & 1u)) >> 16;
    return (unsigned short)r;
}
__device__ __forceinline__ float bf2f(unsigned short b) {
    unsigned u = ((unsigned)b) << 16;
    return __builtin_bit_cast(float, u);
}
__device__ __forceinline__ unsigned pack2(float a, float b) {
    return (unsigned)f2bf(a) | ((unsigned)f2bf(b) << 16);
}
// native transcendentals (guaranteed v_exp/v_log/v_rcp, no lib sequence)
__device__ __forceinline__ float nexp(float x) {
    return __builtin_amdgcn_exp2f(x * 1.4426950408889634f);
}
__device__ __forceinline__ float nlog(float x) {
    return __builtin_amdgcn_logf(x) * 0.6931471805599453f;
}
__device__ __forceinline__ float nrcp(float x) {
    return __builtin_amdgcn_rcpf(x);
}

// mlds stored-pos p (hi*32 + nf*4 + r) -> true feature  (for agg write)
__device__ __forceinline__ int posFeat(int p) {
    return ((p >> 2) & 7) * 16 + ((p >> 5) << 2) + (p & 3);
}
// P stored-pos p (i*32 + hi*8 + j) -> true feature  (line-coalesced gather layout)
__device__ __forceinline__ int posFeat2(int p) {
    int q = ((p >> 5) << 3) | (p & 7);
    return ((q >> 2) << 4) + (((p >> 3) & 3) << 2) + (q & 3);
}

// ===== unified all-bf16 MFMA GEMM: A[M][K] bf16, Bt[NT*64][K] bf16 ([n][k]) =====
template<int K, int NT, int RELU, int BIAS, int OUTMODE>
__global__ __launch_bounds__(256) void gemm_bbg_kernel(
    const unsigned short* __restrict__ Abf, const unsigned short* __restrict__ Bt,
    const float* __restrict__ bias, void* __restrict__ Cout, void* __restrict__ Cout2, int M)
{
    __shared__ short Alds[64][K + 8];
    __shared__ short Blds[64][K + 8];
    const int tid = threadIdx.x;
    const int m0 = blockIdx.x * 64;
    constexpr int SEG = K / 8;
    constexpr int Nc = NT * 64;

    for (int i = tid; i < 64 * SEG; i += 256) {
        int r = i / SEG, sg = i - r * SEG;
        int row = m0 + r;
        short8 va = (row < M) ? *(const short8*)&Abf[(size_t)row * K + sg * 8] : (short8)0;
        *(short8*)&Alds[r][sg * 8] = va;
    }

    const int wv = tid >> 6, lane = tid & 63;
    const int lr = lane & 15, lk = (lane >> 4) * 8;

    for (int nt = 0; nt < NT; ++nt) {
        __syncthreads();   // prev tile consumed (also orders A-stage at nt=0)
        for (int i = tid; i < 64 * SEG; i += 256) {
            int r = i / SEG, sg = i - r * SEG;
            *(short8*)&Blds[r][sg * 8] = *(const short8*)&Bt[(size_t)(nt * 64 + r) * K + sg * 8];
        }
        __syncthreads();

        f32x4 acc[4];
#pragma unroll
        for (int i = 0; i < 4; ++i) acc[i] = (f32x4)0.f;
#pragma unroll
        for (int k0 = 0; k0 < K; k0 += 32) {
            short8 a = *(const short8*)&Alds[wv * 16 + lr][k0 + lk];
#pragma unroll
            for (int nf = 0; nf < 4; ++nf) {
                short8 b = *(const short8*)&Blds[nf * 16 + lr][k0 + lk];
                acc[nf] = __builtin_amdgcn_mfma_f32_16x16x32_bf16(a, b, acc[nf], 0, 0, 0);
            }
        }
#pragma unroll
        for (int nf = 0; nf < 4; ++nf) {
#pragma unroll
            for (int r = 0; r < 4; ++r) {
                int row = m0 + wv * 16 + (lane >> 4) * 4 + r;
                int col = nt * 64 + nf * 16 + lr;
                if (row < M) {
                    float v = acc[nf][r];
                    if (BIAS) v += bias[col];
                    if (RELU) v = fmaxf(v, 0.f);
                    if (OUTMODE == 1) {
                        ((unsigned short*)Cout)[(size_t)row * Nc + col] = f2bf(v);
                    } else {
                        ((float*)Cout)[(size_t)row * Nc + col] = v;
                        ((unsigned short*)Cout2)[(size_t)row * Nc + col] = f2bf(v);
                    }
                }
            }
        }
    }
}

// -------- x fp32 [N][92] -> bf16 padded [N][96] --------
__global__ __launch_bounds__(256) void x2bf_kernel(
    const float* __restrict__ x, unsigned short* __restrict__ xbf)
{
    int i = blockIdx.x * 256 + threadIdx.x;
    if (i >= N_NODES * 96) return;
    int row = i / 96, k = i - row * 96;
    float v = (k < FIN) ? __builtin_nontemporal_load(&x[(size_t)row * FIN + k]) : 0.f;
    xbf[i] = f2bf(v);
}

// -------- build transposed bf16 embed weights w0T[128][96], w1T[128][128] --------
__global__ __launch_bounds__(256) void build_wemb_kernel(
    const float* __restrict__ w_emb0, const float* __restrict__ w_emb1,
    unsigned short* __restrict__ w0T, unsigned short* __restrict__ w1T)
{
    int i = blockIdx.x * 256 + threadIdx.x;
    if (i < 128 * 96) {
        int n = i / 96, k = i - n * 96;
        w0T[i] = (k < FIN) ? f2bf(w_emb0[(size_t)k * FD + n]) : 0;
    }
    if (i < 128 * 128) {
        int n = i >> 7, k = i & 127;
        w1T[i] = f2bf(w_emb1[(size_t)k * FD + n]);
    }
}

// -------- build col-PERMUTED bf16 node-proj weights BcatT[l][512][128] + bias bcatF[l][512] --
__global__ __launch_bounds__(256) void build_bcatT_kernel(
    const float* __restrict__ wf, const float* __restrict__ wsw,
    const float* __restrict__ bfb, const float* __restrict__ bsb,
    unsigned short* __restrict__ BcatT, float* __restrict__ bcatF)
{
    int i = blockIdx.x * 256 + threadIdx.x;
    if (i < NL * 512 * 128) {
        int l = i / (512 * 128);
        int r = i - l * 512 * 128;
        int n = r >> 7, k = r & 127;
        int seg = n >> 7, p = n & 127;
        int nf_ = seg * 128 + posFeat2(p);
        const float* Wm = (nf_ < 256) ? wf : wsw;
        int jj = nf_ & 255;
        int krow = (jj < 128) ? k : (128 + k);
        int col = jj & 127;
        BcatT[i] = f2bf(Wm[((size_t)l * 306 + krow) * FD + col]);
    }
    if (i < NL * 512) {
        int l = i >> 9, n = i & 511;
        int seg = n >> 7, p = n & 127;
        float v = 0.f;
        if (seg == 0) v = bfb[l * FD + posFeat2(p)];
        else if (seg == 2) v = bsb[l * FD + posFeat2(p)];
        bcatF[i] = v;
    }
}

// -------- build transposed bf16 edge-proj weights WecatT[l][256][64] --------
__global__ __launch_bounds__(256) void build_wecat_kernel(
    const float* __restrict__ wf, const float* __restrict__ wsw,
    unsigned short* __restrict__ WecatT)
{
    int i = blockIdx.x * 256 + threadIdx.x;
    if (i >= NL * 256 * 64) return;
    int l = i / (256 * 64);
    int r = i - l * 256 * 64;
    int col = r >> 6, k = r & 63;
    float v = 0.f;
    if (k < DE) {
        const float* W = (col < 128) ? wf : wsw;
        v = W[((size_t)l * 306 + 256 + k) * FD + (col & 127)];
    }
    WecatT[i] = f2bf(v);
}

// ================= dst-sorted edge permutation (counting sort) =================
__global__ __launch_bounds__(256) void hist_kernel(
    const int* __restrict__ dstIdx, int* __restrict__ counts)
{
    int e = blockIdx.x * 256 + threadIdx.x;
    if (e < N_EDGES) atomicAdd(&counts[dstIdx[e]], 1);
}

__global__ __launch_bounds__(1024) void scan_kernel(
    const int* __restrict__ counts, int* __restrict__ cursor)
{
    __shared__ int part[1024];
    const int t = threadIdx.x;
    const int CH = 49;  // 1024*49 >= 50000
    const int base = t * CH;
    int s = 0;
    for (int i = 0; i < CH; ++i) {
        int idx = base + i;
        if (idx < N_NODES) s += counts[idx];
    }
    part[t] = s;
    __syncthreads();
    int v = s;
    for (int off = 1; off < 1024; off <<= 1) {
        int add = (t >= off) ? part[t - off] : 0;
        __syncthreads();
        v += add;
        part[t] = v;
        __syncthreads();
    }
    int pre = (t == 0) ? 0 : part[t - 1];
    for (int i = 0; i < CH; ++i) {
        int idx = base + i;
        if (idx < N_NODES) {
            cursor[idx] = pre;
            pre += counts[idx];
        }
    }
}

__global__ __launch_bounds__(256) void scatter_kernel(
    const int* __restrict__ eidx, int* __restrict__ cursor,
    int* __restrict__ perm, int* __restrict__ srcS, int* __restrict__ dstS)
{
    int e = blockIdx.x * 256 + threadIdx.x;
    if (e >= N_EDGES) return;
    int d = eidx[N_EDGES + e];
    int pos = atomicAdd(&cursor[d], 1);
    perm[pos] = e;
    srcS[pos] = eidx[e];
    dstS[pos] = d;
}

// -------- edge_attr -> bf16 padded [E][64], dst-sorted; u64 loads + packed u32 stores -----
__global__ __launch_bounds__(256) void ea2bf2_kernel(
    const float* __restrict__ ea, const int* __restrict__ perm,
    unsigned* __restrict__ out)
{
    int t = blockIdx.x * 256 + threadIdx.x;   // (edge, j) with j < 32 u32-slots
    if (t >= N_EDGES * 32) return;
    int e = t >> 5, j = t & 31;
    unsigned v = 0;
    if (j < 25) {
        int pe = perm[e];
        unsigned long long u = __builtin_nontemporal_load(
            (const unsigned long long*)(ea + (size_t)pe * DE) + j);
        float lo = __builtin_bit_cast(float, (unsigned)u);
        float hi = __builtin_bit_cast(float, (unsigned)(u >> 32));
        v = pack2(lo, hi);
    }
    out[(size_t)e * 32 + j] = v;
}

// ===== msg15n10: zero-barrier wave-independent + native transcendentals, NW=10 =====
// Wave w owns edges [base + w*WEDGE, base + (w+1)*WEDGE) as NW windows of 16.
__global__ __launch_bounds__(128) void msg15n10_kernel(
    const unsigned short* __restrict__ Pbf,     // [N][512] bf16, posFeat2-permuted per 128-seg
    const unsigned short* __restrict__ eabf,    // [E][64] bf16, dst-sorted
    const unsigned short* __restrict__ WecatT,  // [256][64] bf16 (layer offset applied)
    const int* __restrict__ srcS, const int* __restrict__ dstS,
    float* __restrict__ agg)
{
    __shared__ float mlds[2][16][MPAD];
    __shared__ int dlds[BEDGE + 2];
    const int tid = threadIdx.x;
    const int base = blockIdx.x * BEDGE;

    for (int i = tid; i < BEDGE + 2; i += 128) {
        int ge = base - 1 + i;
        int v;
        if (ge < 0) v = -1;
        else if (ge >= N_EDGES) v = -2;
        else v = __builtin_nontemporal_load(&dstS[ge]);
        dlds[i] = v;
    }

    const int w = tid >> 6, lane = tid & 63;
    const int lr = lane & 15, hi = lane >> 4;
    const int wspan = w * WEDGE;              // wave's first edge (block-local)

    int s_cur = __builtin_nontemporal_load(&srcS[base + wspan + lr]);
    short8 b0_cur = __builtin_nontemporal_load((const short8*)&eabf[(size_t)(base + wspan + lr) * 64 + hi * 8]);
    short8 b1_cur = __builtin_nontemporal_load((const short8*)&eabf[(size_t)(base + wspan + lr) * 64 + 32 + hi * 8]);

    __syncthreads();   // dlds ready (only barrier in the kernel)

    float run0 = 0.f, run1 = 0.f;
    bool startsInside = (dlds[wspan + 1] != dlds[wspan]);
    const int fc0 = posFeat(lane);
    const int fc1 = posFeat(lane + 64);

#pragma unroll 1
    for (int wi = 0; wi < NW; ++wi) {
        const int jbase = wspan + wi * 16;
        const int d = dlds[1 + jbase + lr];
        const int s = s_cur;
        const short8 b0 = b0_cur, b1 = b1_cur;

        if (wi + 1 < NW) {
            const int en = base + jbase + 16 + lr;
            s_cur = __builtin_nontemporal_load(&srcS[en]);
            b0_cur = __builtin_nontemporal_load((const short8*)&eabf[(size_t)en * 64 + hi * 8]);
            b1_cur = __builtin_nontemporal_load((const short8*)&eabf[(size_t)en * 64 + 32 + hi * 8]);
        }

        const unsigned short* pdrow = Pbf + (size_t)d * 512 + hi * 8;
        const unsigned short* psrow = Pbf + (size_t)s * 512 + hi * 8;

        // ---- pass S ----
        unsigned pvp[16];
        {
            short8 pds[4], pss[4];
#pragma unroll
            for (int i = 0; i < 4; ++i) {
                pds[i] = *(const short8*)(pdrow + 256 + i * 32);
                pss[i] = *(const short8*)(psrow + 384 + i * 32);
            }
            f32x4 accS[8];
#pragma unroll
            for (int i = 0; i < 8; ++i) accS[i] = (f32x4)0.f;
#pragma unroll
            for (int nf = 0; nf < 8; ++nf) {
                short8 a0 = *(const short8*)&WecatT[(size_t)((nf + 8) * 16 + lr) * 64 + hi * 8];
                short8 a1 = *(const short8*)&WecatT[(size_t)((nf + 8) * 16 + lr) * 64 + 32 + hi * 8];
                accS[nf] = __builtin_amdgcn_mfma_f32_16x16x32_bf16(a0, b0, accS[nf], 0, 0, 0);
                accS[nf] = __builtin_amdgcn_mfma_f32_16x16x32_bf16(a1, b1, accS[nf], 0, 0, 0);
            }
#pragma unroll
            for (int j = 0; j < 16; ++j) {
                const int k0 = 2 * j, k1 = 2 * j + 1;
                float v0 = accS[k0 >> 2][k0 & 3] + bf2f((unsigned short)pds[k0 >> 3][k0 & 7])
                                                 + bf2f((unsigned short)pss[k0 >> 3][k0 & 7]);
                float v1 = accS[k1 >> 2][k1 & 3] + bf2f((unsigned short)pds[k1 >> 3][k1 & 7])
                                                 + bf2f((unsigned short)pss[k1 >> 3][k1 & 7]);
                pvp[j] = pack2(v0, v1);
            }
        }

        // ---- pass F (native-transcendental gate) ----
        {
            short8 pdf[4], psf[4];
#pragma unroll
            for (int i = 0; i < 4; ++i) {
                pdf[i] = *(const short8*)(pdrow + i * 32);
                psf[i] = *(const short8*)(psrow + 128 + i * 32);
            }
            f32x4 accF[8];
#pragma unroll
            for (int i = 0; i < 8; ++i) accF[i] = (f32x4)0.f;
#pragma unroll
            for (int nf = 0; nf < 8; ++nf) {
                short8 a0 = *(const short8*)&WecatT[(size_t)(nf * 16 + lr) * 64 + hi * 8];
                short8 a1 = *(const short8*)&WecatT[(size_t)(nf * 16 + lr) * 64 + 32 + hi * 8];
                accF[nf] = __builtin_amdgcn_mfma_f32_16x16x32_bf16(a0, b0, accF[nf], 0, 0, 0);
                accF[nf] = __builtin_amdgcn_mfma_f32_16x16x32_bf16(a1, b1, accF[nf], 0, 0, 0);
            }
#pragma unroll
            for (int nf = 0; nf < 8; ++nf) {
                f32x4 m;
#pragma unroll
                for (int r = 0; r < 4; ++r) {
                    const int q = nf * 4 + r;
                    float pf = accF[nf][r] + bf2f((unsigned short)pdf[q >> 3][q & 7])
                                           + bf2f((unsigned short)psf[q >> 3][q & 7]);
                    unsigned pw = pvp[q >> 1];
                    float pv = (q & 1) ? __builtin_bit_cast(float, pw & 0xFFFF0000u)
                                       : bf2f((unsigned short)(pw & 0xFFFFu));
                    float sig = nrcp(1.f + nexp(-pf));            // v_rcp + v_exp
                    float tt = nexp(-fabsf(pv));                  // v_exp
                    float sp = fmaxf(pv, 0.f) + nlog(1.f + tt);   // v_log
                    m[r] = sig * sp;
                }
                *(f32x4*)&mlds[w][lr][hi * 32 + nf * 4] = m;
            }
        }
        // no barrier: wave-internal LDS ordering (lgkmcnt)

        // ---- phase 2 ----
        {
#pragma unroll 4
            for (int ee = 0; ee < 16; ++ee) {
                const int j = jbase + ee;
                run0 += mlds[w][ee][lane];
                run1 += mlds[w][ee][lane + 64];
                int de = dlds[j + 1];
                int dnext = dlds[j + 2];
                if (de != dnext) {
                    if (startsInside) {
                        agg[(size_t)de * FD + fc0] = run0;
                        agg[(size_t)de * FD + fc1] = run1;
                    } else {
                        unsafeAtomicAdd(&agg[(size_t)de * FD + fc0], run0);
                        unsafeAtomicAdd(&agg[(size_t)de * FD + fc1], run1);
                    }
                    run0 = 0.f; run1 = 0.f;
                    startsInside = true;
                }
            }
        }
    }
    if (run0 != 0.f || run1 != 0.f) {
        unsafeAtomicAdd(&agg[(size_t)dlds[wspan + WEDGE] * FD + fc0], run0);
        unsafeAtomicAdd(&agg[(size_t)dlds[wspan + WEDGE] * FD + fc1], run1);
    }
}

// -------- BatchNorm stats over N rows (LDS pair-reduce, then one atomic per col) --------
__global__ __launch_bounds__(256) void bn_stats_kernel(
    const float* __restrict__ agg, float* __restrict__ stats)
{
    __shared__ float sl[256], sql[256];
    const int tid = threadIdx.x;
    const int f = tid & 127;
    float s = 0.f, sq = 0.f;
    for (int row = blockIdx.x * 2 + (tid >> 7); row < N_NODES; row += gridDim.x * 2) {
        float v = agg[(size_t)row * FD + f];
        s += v; sq += v * v;
    }
    sl[tid] = s; sql[tid] = sq;
    __syncthreads();
    if (tid < 128) {
        unsafeAtomicAdd(&stats[f], sl[tid] + sl[tid + 128]);
        unsafeAtomicAdd(&stats[128 + f], sql[tid] + sql[tid + 128]);
    }
}

// -------- h = relu(h + BN(agg)); write fp32 + bf16; atomicMax per-graph --------
__global__ __launch_bounds__(256) void bn_update_kernel(
    float* __restrict__ h, unsigned short* __restrict__ hbf,
    const float* __restrict__ agg,
    const float* __restrict__ stats, const float* __restrict__ g,
    const float* __restrict__ b, const int* __restrict__ batch,
    float* __restrict__ gmax)
{
    const int tid = threadIdx.x;
    const int row = blockIdx.x * 2 + (tid >> 7);
    if (row >= N_NODES) return;
    const int f = tid & 127;
    const float inv = 1.f / (float)N_NODES;
    float mu = stats[f] * inv;
    float var = stats[128 + f] * inv - mu * mu;
    float rs = rsqrtf(var + 1e-5f);
    size_t idx = (size_t)row * FD + f;
    float v = h[idx] + (agg[idx] - mu) * rs * g[f] + b[f];
    v = fmaxf(v, 0.f);
    h[idx] = v;
    hbf[idx] = f2bf(v);
    atomicMax((unsigned*)&gmax[batch[row] * FD + f], __float_as_uint(v));
}

// -------- final layer: gmax only (h/hbf dead afterwards) --------
__global__ __launch_bounds__(256) void bn_gmax_kernel(
    const float* __restrict__ h, const float* __restrict__ agg,
    const float* __restrict__ stats, const float* __restrict__ g,
    const float* __restrict__ b, const int* __restrict__ batch,
    float* __restrict__ gmax)
{
    const int tid = threadIdx.x;
    const int row = blockIdx.x * 2 + (tid >> 7);
    if (row >= N_NODES) return;
    const int f = tid & 127;
    const float inv = 1.f / (float)N_NODES;
    float mu = stats[f] * inv;
    float var = stats[128 + f] * inv - mu * mu;
    float rs = rsqrtf(var + 1e-5f);
    size_t idx = (size_t)row * FD + f;
    float v = h[idx] + (agg[idx] - mu) * rs * g[f] + b[f];
    v = fmaxf(v, 0.f);
    atomicMax((unsigned*)&gmax[batch[row] * FD + f], __float_as_uint(v));
}

__global__ __launch_bounds__(256) void gf_acc_kernel(float* __restrict__ gf, const float* __restrict__ gmax)
{
    int i = blockIdx.x * 256 + threadIdx.x;
    gf[i] += gmax[i];
}

// -------- head --------
__global__ __launch_bounds__(128) void head_y_kernel(
    const float* __restrict__ gf, const float* __restrict__ w1,
    const float* __restrict__ b1, float* __restrict__ y)
{
    __shared__ float row[128];
    int g = blockIdx.x, j = threadIdx.x;
    row[j] = gf[g * FD + j];
    __syncthreads();
    float acc = b1[j];
    for (int k = 0; k < FD; ++k) acc = fmaf(row[k], w1[k * FD + j], acc);
    y[g * FD + j] = acc;
}

__global__ __launch_bounds__(128) void head_stats_kernel(
    const float* __restrict__ y, float* __restrict__ hstat)
{
    int f = threadIdx.x;
    float s = 0.f, sq = 0.f;
    for (int g = 0; g < NG; ++g) { float v = y[g * FD + f]; s += v; sq += v * v; }
    float mu = s / (float)NG;
    float var = sq / (float)NG - mu * mu;
    hstat[f] = mu;
    hstat[128 + f] = rsqrtf(var + 1e-5f);
}

__global__ __launch_bounds__(128) void head_out_kernel(
    const float* __restrict__ y, const float* __restrict__ hstat,
    const float* __restrict__ bng, const float* __restrict__ bnb,
    const float* __restrict__ w2, const float* __restrict__ b2,
    float* __restrict__ out)
{
    __shared__ float part[2];
    int g = blockIdx.x, f = threadIdx.x;
    float v = (y[g * FD + f] - hstat[f]) * hstat[128 + f] * bng[f] + bnb[f];
    v = fmaxf(v, 0.f) * w2[f];
    for (int o = 32; o > 0; o >>= 1) v += __shfl_down(v, o);
    if ((f & 63) == 0) part[f >> 6] = v;
    __syncthreads();
    if (f == 0) out[g] = part[0] + part[1] + b2[0];
}

extern "C" void kernel_launch(void* const* d_in, const int* in_sizes, int n_in,
                              void* d_out, int out_size, void* d_ws, size_t ws_size,
                              hipStream_t stream)
{
    const float* x        = (const float*)d_in[0];
    const float* edge_attr= (const float*)d_in[1];
    const float* w_emb0   = (const float*)d_in[2];
    const float* w_emb1   = (const float*)d_in[3];
    const float* wf       = (const float*)d_in[4];
    const float* bf       = (const float*)d_in[5];
    const float* wsw      = (const float*)d_in[6];
    const float* bs       = (const float*)d_in[7];
    const float* bn_g     = (const float*)d_in[8];
    const float* bn_b     = (const float*)d_in[9];
    const float* w1       = (const float*)d_in[10];
    const float* b1       = (const float*)d_in[11];
    const float* bng      = (const float*)d_in[12];
    const float* bnb      = (const float*)d_in[13];
    const float* w2       = (const float*)d_in[14];
    const float* b2       = (const float*)d_in[15];
    const int*   eidx     = (const int*)d_in[16];   // [2][E]: row0=src, row1=dst
    const int*   batch    = (const int*)d_in[17];

    char* base = (char*)d_ws;
    size_t off = 0;
    auto alloc = [&](size_t bytes) -> void* {
        void* p = base + off;
        off += (bytes + 255) & ~(size_t)255;
        return p;
    };
    float*          h      = (float*)alloc((size_t)N_NODES * FD * 4);
    unsigned short* hbf    = (unsigned short*)alloc((size_t)N_NODES * FD * 2);
    unsigned short* Pbf    = (unsigned short*)alloc((size_t)N_NODES * 512 * 2);
    // agg|stats|gmax contiguous -> single per-layer memset
    float*          agg    = (float*)alloc((size_t)N_NODES * FD * 4);   // also embed tmp + sort scratch
    float*          stats  = (float*)alloc(256 * 4);
    float*          gmax   = (float*)alloc((size_t)NG * FD * 4);
    unsigned short* BcatT  = (unsigned short*)alloc((size_t)NL * 512 * 128 * 2);
    unsigned short* WecatT = (unsigned short*)alloc((size_t)NL * 256 * 64 * 2);
    float*          bcatF  = (float*)alloc((size_t)NL * 512 * 4);
    unsigned short* eabf   = (unsigned short*)alloc((size_t)N_EDGES * 64 * 2);
    int*            srcS   = (int*)alloc((size_t)N_EDGES * 4);
    int*            dstS   = (int*)alloc((size_t)N_EDGES * 4);
    unsigned short* xbf    = (unsigned short*)alloc((size_t)N_NODES * 96 * 2);
    unsigned short* w0T    = (unsigned short*)alloc((size_t)128 * 96 * 2);
    unsigned short* w1T    = (unsigned short*)alloc((size_t)128 * 128 * 2);
    float*          gf     = (float*)alloc((size_t)NG * FD * 4);
    float*          y      = (float*)alloc((size_t)NG * FD * 4);
    float*          hstat  = (float*)alloc(256 * 4);

    const size_t msetBytes = (size_t)((char*)gmax + (size_t)NG * FD * 4 - (char*)agg);

    // sort scratch overlaid on agg (dead until layer loop; all sort users complete first)
    int* perm   = (int*)agg;               // [E]
    int* counts = perm + N_EDGES;          // [N]
    int* cursor = counts + N_NODES;        // [N]
    // t0 (embed intermediate, bf16 [N][128]) also overlays agg (after ea2bf consumed perm)
    unsigned short* t0bf = (unsigned short*)agg;

    const int MB = (N_NODES + 63) / 64;  // 782

    // ---- dst-sort the edges (once, reused across layers) ----
    hipMemsetAsync(counts, 0, (size_t)N_NODES * 4, stream);
    hist_kernel<<<(N_EDGES + 255) / 256, 256, 0, stream>>>(eidx + N_EDGES, counts);
    scan_kernel<<<1, 1024, 0, stream>>>(counts, cursor);
    scatter_kernel<<<(N_EDGES + 255) / 256, 256, 0, stream>>>(eidx, cursor, perm, srcS, dstS);
    ea2bf2_kernel<<<(N_EDGES * 32) / 256, 256, 0, stream>>>(edge_attr, perm, (unsigned*)eabf);

    build_bcatT_kernel<<<(NL * 512 * 128 + 255) / 256, 256, 0, stream>>>(wf, wsw, bf, bs, BcatT, bcatF);
    build_wecat_kernel<<<(NL * 256 * 64 + 255) / 256, 256, 0, stream>>>(wf, wsw, WecatT);
    build_wemb_kernel<<<64, 256, 0, stream>>>(w_emb0, w_emb1, w0T, w1T);
    x2bf_kernel<<<(N_NODES * 96 + 255) / 256, 256, 0, stream>>>(x, xbf);

    // embedding MLP (all-bf16 GEMMs): t0 = relu(xbf@w0); h(+hbf) = t0@w1
    gemm_bbg_kernel<96, 2, 1, 0, 1><<<MB, 256, 0, stream>>>(xbf, w0T, nullptr, t0bf, nullptr, N_NODES);
    gemm_bbg_kernel<128, 2, 0, 0, 2><<<MB, 256, 0, stream>>>(t0bf, w1T, nullptr, h, hbf, N_NODES);

    hipMemsetAsync(gf, 0, (size_t)NG * FD * 4, stream);

    for (int l = 0; l < NL; ++l) {
        hipMemsetAsync(agg, 0, msetBytes, stream);   // zeros agg + stats + gmax

        // P = hbf @ BcatT[l]^T + bcatF[l]  -> bf16 [N][512], posFeat2-permuted
        gemm_bbg_kernel<128, 8, 0, 1, 1><<<MB, 256, 0, stream>>>(
            hbf, BcatT + (size_t)l * 512 * 128, bcatF + (size_t)l * 512, Pbf, nullptr, N_NODES);

        msg15n10_kernel<<<N_EDGES / BEDGE, 128, 0, stream>>>(
            Pbf, eabf, WecatT + (size_t)l * 256 * 64, srcS, dstS, agg);

        bn_stats_kernel<<<256, 256, 0, stream>>>(agg, stats);
        if (l < NL - 1) {
            bn_update_kernel<<<(N_NODES + 1) / 2, 256, 0, stream>>>(
                h, hbf, agg, stats, bn_g + l * FD, bn_b + l * FD, batch, gmax);
        } else {
            bn_gmax_kernel<<<(N_NODES + 1) / 2, 256, 0, stream>>>(
                h, agg, stats, bn_g + l * FD, bn_b + l * FD, batch, gmax);
        }
        gf_acc_kernel<<<(NG * FD) / 256, 256, 0, stream>>>(gf, gmax);
    }

    head_y_kernel<<<NG, 128, 0, stream>>>(gf, w1, b1, y);
    head_stats_kernel<<<1, 128, 0, stream>>>(y, hstat);
    head_out_kernel<<<NG, 128, 0, stream>>>(y, hstat, bng, bnb, w2, b2, (float*)d_out);
}